// Round 10
// baseline (439.331 us; speedup 1.0000x reference)
//
#include <hip/hip_runtime.h>

// ChunkedLSAttention on MI355X (gfx950).
// B=4, L=2048, D=1024, H=16, DH=64, W=128, CS=32, NCC=NCB=64, NC=128, NQ=64.
// All inputs/outputs f32. bf16 for all MFMA operands (f32 accumulate).
// kbp/vbp stored bf16. Mask: masked iff ci-64 >= qc.
// GEMM LDS tiles XOR bank-swizzled (pre-swizzled global src + swizzled read).
// Attention grid (h, qc, b): h fastest -> 16 consecutive blocks share kwb/vwT
// rows -> full L2-line consumption.
// Small GEMMs folded into other launches: 4 independent jobs ride in the
// scores launch (z=2); the 2 hcm-dependent jobs ride in gemm_qkv_big (bn=12,
// waves 4-7 mirror waves 0-3 -- duplicated identical work, benign).

typedef unsigned short u16;
typedef __attribute__((ext_vector_type(8))) short short8;
typedef __attribute__((ext_vector_type(4))) float f32x4;

#define NEGINF -1e30f

__device__ __forceinline__ float bf2f(u16 u) {
    union { unsigned int i; float f; } v; v.i = ((unsigned int)u) << 16; return v.f;
}
__device__ __forceinline__ u16 f2bf(float f) {
    union { float fl; unsigned int i; } v; v.fl = f;
    unsigned int x = v.i;
    return (u16)((x + 0x7fffu + ((x >> 16) & 1u)) >> 16);   // RNE
}
__device__ __forceinline__ short8 ldg8(const u16* p) { return *(const short8*)p; }

// async global->LDS, 16B per lane; LDS dest = wave-uniform base + lane*16.
__device__ __forceinline__ void async16(const u16* g, u16* l) {
    __builtin_amdgcn_global_load_lds(
        (const __attribute__((address_space(1))) unsigned int*)g,
        (__attribute__((address_space(3))) unsigned int*)l, 16, 0, 0);
}

// ---------------------------------------------------------------------------
// Shared-LDS 128x128 m97-style GEMM tile (4-wave semantics; callable from
// 512-thread blocks: wv masked &3 so twin waves duplicate identical work).
// A/C pointers pre-offset by caller. C = A @ Bt^T * scale + bias.
// ---------------------------------------------------------------------------
__device__ void gemm128p(u16* As, u16* Bs,
    const u16* __restrict__ A, const u16* __restrict__ Bt,
    float* Cf, u16* Cb, const float* bias, float scale,
    int bm, int bn, int N, int K)
{
    const int tid = threadIdx.x;
    const int lane = tid & 63, wv = (tid >> 6) & 3;
    const int l15 = lane & 15, quad = lane >> 4;
    const int wm = (wv & 1) * 64, wn = (wv >> 1) * 64;

    f32x4 acc[4][4];
    #pragma unroll
    for (int i = 0; i < 4; ++i)
        #pragma unroll
        for (int jx = 0; jx < 4; ++jx) acc[i][jx] = (f32x4){0.f, 0.f, 0.f, 0.f};

    const int srow = wv * 32 + (lane >> 2);
    const int scol = (lane & 3) * 8;
    const u16* a_src  = A  + (long)(bm * 128 + srow) * K + scol;
    const u16* a_src2 = a_src + (long)16 * K;
    const u16* b_src  = Bt + (long)(bn * 128 + srow) * K + scol;
    const u16* b_src2 = b_src + (long)16 * K;
    u16* lA0 = &As[(wv * 32) * 32];
    u16* lA1 = &As[(wv * 32 + 16) * 32];
    u16* lB0 = &Bs[(wv * 32) * 32];
    u16* lB1 = &Bs[(wv * 32 + 16) * 32];

    for (int k0 = 0; k0 < K; k0 += 32) {
        async16(a_src, lA0); async16(a_src2, lA1);
        async16(b_src, lB0); async16(b_src2, lB1);
        a_src += 32; a_src2 += 32; b_src += 32; b_src2 += 32;
        __syncthreads();
        short8 af[4], bfr[4];
        #pragma unroll
        for (int i = 0; i < 4; ++i)
            af[i] = *(const short8*)&As[(wm + i * 16 + l15) * 32 + quad * 8];
        #pragma unroll
        for (int jx = 0; jx < 4; ++jx)
            bfr[jx] = *(const short8*)&Bs[(wn + jx * 16 + l15) * 32 + quad * 8];
        #pragma unroll
        for (int i = 0; i < 4; ++i)
            #pragma unroll
            for (int jx = 0; jx < 4; ++jx)
                acc[i][jx] = __builtin_amdgcn_mfma_f32_16x16x32_bf16(af[i], bfr[jx], acc[i][jx], 0, 0, 0);
        __syncthreads();
    }

    #pragma unroll
    for (int i = 0; i < 4; ++i) {
        #pragma unroll
        for (int jx = 0; jx < 4; ++jx) {
            int col = bn * 128 + wn + jx * 16 + l15;
            float bsv = bias ? bias[col] : 0.f;
            #pragma unroll
            for (int r = 0; r < 4; ++r) {
                int row = bm * 128 + wm + i * 16 + quad * 4 + r;
                float v = acc[i][jx][r] * scale + bsv;
                long idx = (long)row * N + col;
                if (Cf) Cf[idx] = v;
                if (Cb) Cb[idx] = f2bf(v);
            }
        }
    }
}

// ---------------------------------------------------------------------------
// All casts + six weight transposes in ONE launch. grid = 15168.
// ---------------------------------------------------------------------------
__global__ __launch_bounds__(256) void cast_fuse(
    const float* __restrict__ h, const float* __restrict__ hc,
    const float* __restrict__ pos_w, const float* __restrict__ key_pe,
    const float* __restrict__ Wd,
    u16* __restrict__ hB, u16* __restrict__ hcwB,
    u16* __restrict__ pwB, u16* __restrict__ kpeB, u16* __restrict__ WdB,
    const float* __restrict__ W0, const float* __restrict__ W1,
    const float* __restrict__ W2, const float* __restrict__ W3,
    const float* __restrict__ W4, const float* __restrict__ W5,
    u16* __restrict__ D0, u16* __restrict__ D1, u16* __restrict__ D2,
    u16* __restrict__ D3, u16* __restrict__ D4, u16* __restrict__ D5)
{
    const int bx = blockIdx.x, tid = threadIdx.x;
    __shared__ float t[32][33];

    if (bx < 8192) {
        int i = bx * 256 + tid;
        float4 v = ((const float4*)h)[i];
        u16* o = hB + (long)i * 4;
        o[0] = f2bf(v.x); o[1] = f2bf(v.y); o[2] = f2bf(v.z); o[3] = f2bf(v.w);
    } else if (bx < 8704) {
        int i = (bx - 8192) * 256 + tid;
        int flat = i * 4;
        int b = flat >> 17, r = (flat >> 10) & 127, c = flat & 1023;
        float4 v = *(const float4*)(hc + ((long)b * 2048 + 1920 + r) * 1024 + c);
        u16* o = hcwB + (long)flat;
        o[0] = f2bf(v.x); o[1] = f2bf(v.y); o[2] = f2bf(v.z); o[3] = f2bf(v.w);
    } else if (bx < 8832) {
        int i = (bx - 8704) * 256 + tid;
        float4 v = ((const float4*)pos_w)[i];
        u16* o = pwB + (long)i * 4;
        o[0] = f2bf(v.x); o[1] = f2bf(v.y); o[2] = f2bf(v.z); o[3] = f2bf(v.w);
    } else if (bx < 8960) {
        int i = (bx - 8832) * 256 + tid;
        float4 v = ((const float4*)key_pe)[i];
        u16* o = kpeB + (long)i * 4;
        o[0] = f2bf(v.x); o[1] = f2bf(v.y); o[2] = f2bf(v.z); o[3] = f2bf(v.w);
    } else if (bx < 9024) {
        int e = (bx - 8960) * 256 + tid;
        if (e < 16384) WdB[(e & 15) * 1024 + (e >> 4)] = f2bf(Wd[e]);
    } else {
        const int t6 = bx - 9024;
        const int z = t6 >> 10;
        const int rem = t6 & 1023;
        const int bxx = rem & 31, byy = rem >> 5;
        const float* W = (z == 0) ? W0 : (z == 1) ? W1 : (z == 2) ? W2
                       : (z == 3) ? W3 : (z == 4) ? W4 : W5;
        u16* WT = (z == 0) ? D0 : (z == 1) ? D1 : (z == 2) ? D2
                : (z == 3) ? D3 : (z == 4) ? D4 : D5;
        const int tx = tid & 31, ty = tid >> 5;
        #pragma unroll
        for (int p = 0; p < 4; ++p) {
            int k = byy * 32 + ty + p * 8;
            t[ty + p * 8][tx] = W[(long)k * 1024 + bxx * 32 + tx];
        }
        __syncthreads();
        #pragma unroll
        for (int p = 0; p < 4; ++p) {
            int n = ty + p * 8;
            WT[((long)(bxx * 32 + n)) * 1024 + byy * 32 + tx] = f2bf(t[tx][n]);
        }
    }
}

// ---------------------------------------------------------------------------
// Scores (+softmax, +compress) AND the four independent small GEMMs.
// grid=(64, 8, 3), block 256:
//   z=0, by<4 : src = h_cache (f32) -> hcm           (c=bx, b=by)
//   z=1, by<4 : src = hB (bf16)     -> sc_blk        (c=bx, b=by)
//   z=2, bx<10: small GEMM jobs: bx 0-3 jk(bz=bx), 4-7 jv, 8 jt, 9 jc; bn=by.
// ---------------------------------------------------------------------------
__global__ __launch_bounds__(256) void scores_multi(
    const float* __restrict__ hc, const u16* __restrict__ hBp,
    const u16* __restrict__ WdB, const float* __restrict__ bd,
    u16* __restrict__ hcm, float* __restrict__ sc_blk,
    const u16* __restrict__ hcwB, const u16* __restrict__ WkT,
    const u16* __restrict__ WvT,
    float* __restrict__ kcw, float* __restrict__ vcw,
    const u16* __restrict__ pwB, const u16* __restrict__ WrT,
    u16* __restrict__ pos_tb, const float* __restrict__ br,
    const u16* __restrict__ kpeB, const u16* __restrict__ WrcT,
    u16* __restrict__ pos_cb, const float* __restrict__ brc)
{
    __shared__ __align__(16) char sm[76800];

    const int tid = threadIdx.x;

    if (blockIdx.z == 2) {
        const int bx = blockIdx.x, bn = blockIdx.y;
        if (bx >= 10) return;
        u16* As = (u16*)sm;
        u16* Bs = (u16*)(sm + 8192);
        if (bx < 4)
            gemm128p(As, Bs, hcwB + (long)bx * 128 * 1024, WkT,
                     kcw + (long)bx * 128 * 1024, nullptr, nullptr, 1.f, 0, bn, 1024, 1024);
        else if (bx < 8)
            gemm128p(As, Bs, hcwB + (long)(bx - 4) * 128 * 1024, WvT,
                     vcw + (long)(bx - 4) * 128 * 1024, nullptr, nullptr, 1.f, 0, bn, 1024, 1024);
        else if (bx == 8)
            gemm128p(As, Bs, pwB, WrT, nullptr, pos_tb, br, 1.f, 0, bn, 1024, 1024);
        else
            gemm128p(As, Bs, kpeB, WrcT, nullptr, pos_cb, brc, 1.f, 0, bn, 1024, 1024);
        return;
    }

    const int c = blockIdx.x, b = blockIdx.y;
    if (b >= 4) return;
    const bool zc = (blockIdx.z == 0);
    const int lane = tid & 63, wv = tid >> 6;
    const int l15 = lane & 15, quad = lane >> 4;

    u16 (*srcs)[1032]      = (u16 (*)[1032])sm;              // 66048 B
    float (*sred)[32][16]  = (float (*)[32][16])(sm + 66048); // 8192 B
    float (*s_sm)[16]      = (float (*)[16])(sm + 74240);     // 2048 B
    float (*smx)[16]       = (float (*)[16])(sm + 76288);     // 256 B
    float (*ssum)[16]      = (float (*)[16])(sm + 76544);     // 256 B

    if (zc) {
        const float* sb = hc + (long)b * 2048 * 1024 + (long)c * 32 * 1024;
        for (int e = tid; e < 8192; e += 256) {
            int flat = e * 4;
            int row = flat >> 10, col = flat & 1023;
            float4 v = *(const float4*)(sb + (long)row * 1024 + col);
            u16* dp = &srcs[row][col];
            dp[0] = f2bf(v.x); dp[1] = f2bf(v.y); dp[2] = f2bf(v.z); dp[3] = f2bf(v.w);
        }
    } else {
        const u16* sb = hBp + (long)b * 2048 * 1024 + (long)c * 32 * 1024;
        for (int e = tid; e < 4096; e += 256) {
            int flat = e * 8;
            int row = flat >> 10, col = flat & 1023;
            *(short8*)&srcs[row][col] = ldg8(sb + (long)row * 1024 + col);
        }
    }
    __syncthreads();

    // scores MFMA: wave wv covers K [wv*256, wv*256+256)
    {
        f32x4 acc0 = {0.f,0.f,0.f,0.f}, acc1 = {0.f,0.f,0.f,0.f};
        const int kq = wv * 256;
        #pragma unroll
        for (int kc = 0; kc < 8; ++kc) {
            int off = kq + kc * 32 + quad * 8;
            short8 bf_ = ldg8(WdB + (long)l15 * 1024 + off);
            short8 a0 = *(const short8*)&srcs[l15][off];
            short8 a1 = *(const short8*)&srcs[16 + l15][off];
            acc0 = __builtin_amdgcn_mfma_f32_16x16x32_bf16(a0, bf_, acc0, 0, 0, 0);
            acc1 = __builtin_amdgcn_mfma_f32_16x16x32_bf16(a1, bf_, acc1, 0, 0, 0);
        }
        #pragma unroll
        for (int r = 0; r < 4; ++r) {
            sred[wv][quad * 4 + r][l15]      = acc0[r];
            sred[wv][16 + quad * 4 + r][l15] = acc1[r];
        }
    }
    __syncthreads();
    for (int idx = tid; idx < 512; idx += 256) {
        int i = idx >> 4, hd = idx & 15;
        s_sm[i][hd] = bd[hd] + sred[0][i][hd] + sred[1][i][hd]
                            + sred[2][i][hd] + sred[3][i][hd];
    }
    __syncthreads();

    // ---- wave-parallel softmax over 32 rows per head ----
    {
        const int hd = tid & 15, i2 = tid >> 4;
        float a = s_sm[i2][hd], bx2 = s_sm[i2 + 16][hd];
        float m = fmaxf(a, bx2);
        m = fmaxf(m, __shfl_xor(m, 16));
        m = fmaxf(m, __shfl_xor(m, 32));
        if (lane < 16) smx[wv][lane] = m;
        __syncthreads();
        float M = fmaxf(fmaxf(smx[0][hd], smx[1][hd]), fmaxf(smx[2][hd], smx[3][hd]));
        float ea = __expf(a - M), eb = __expf(bx2 - M);
        float s = ea + eb;
        s += __shfl_xor(s, 16);
        s += __shfl_xor(s, 32);
        if (lane < 16) ssum[wv][lane] = s;
        __syncthreads();
        float S = ssum[0][hd] + ssum[1][hd] + ssum[2][hd] + ssum[3][hd];
        float inv = 1.f / S;
        s_sm[i2][hd]      = ea * inv;
        s_sm[i2 + 16][hd] = eb * inv;
    }
    __syncthreads();

    if (!zc) {
        for (int idx = tid; idx < 512; idx += 256) {
            int hd = idx >> 5, i = idx & 31;
            sc_blk[(long)b * (16*64*32) + ((long)hd * 64 + c) * 32 + i] = s_sm[i][hd];
        }
    } else {
        // vectorized compress: thread pair (g, half) owns 8 cols of half rows.
        const int g = tid >> 1, half = tid & 1;     // g in [0,128)
        const int j0 = g * 8;
        const int hd = g >> 3;
        float acc[8] = {0.f,0.f,0.f,0.f,0.f,0.f,0.f,0.f};
        #pragma unroll
        for (int i = 0; i < 16; ++i) {
            const int row = half * 16 + i;
            const float w = s_sm[row][hd];
            short8 sv = *(const short8*)&srcs[row][j0];
            #pragma unroll
            for (int k = 0; k < 8; ++k) acc[k] += w * bf2f((u16)sv[k]);
        }
        #pragma unroll
        for (int k = 0; k < 8; ++k) acc[k] += __shfl_xor(acc[k], 1);
        if (half == 0) {
            u16 o[8];
            #pragma unroll
            for (int k = 0; k < 8; ++k) o[k] = f2bf(acc[k]);
            *(uint4*)&hcm[(long)b * (64*1024) + (long)c * 1024 + j0] = *(const uint4*)o;
        }
    }
}

// ---------------------------------------------------------------------------
// Fused QKV projection, 256x256 tile, 8 waves (512 thr), per-wave 128x64.
// 2 LDS buffers (64 KB), counted-vmcnt pipeline, raw barriers, XOR-swizzled
// LDS tiles. A (8192x1024) @ WqkvT^T (3072x1024). grid=(32,13):
//   bn < 12 : normal QKV tile.
//   bn == 12: the two hcm-dependent 128^2 GEMMs (jkc/jvc), bm encodes
//             (job, bm2, bn2); waves 4-7 mirror 0-3 (identical work).
// ---------------------------------------------------------------------------
__global__ __launch_bounds__(512) void gemm_qkv_big(
    const u16* __restrict__ A, const u16* __restrict__ Bt,
    u16* __restrict__ q_ws, u16* __restrict__ kbp, u16* __restrict__ vbp,
    const u16* __restrict__ hcm, const u16* __restrict__ WkT,
    const u16* __restrict__ WvT,
    float* __restrict__ kc_raw, float* __restrict__ vc_raw)
{
    const int tid = threadIdx.x;
    const int bm = blockIdx.x, bn = blockIdx.y;
    const int K = 1024, NT = 32;

    __shared__ __align__(16) u16 smem[65536 / 2];   // 64 KB
    u16* const As = smem;                            // [2][256*32] u16
    u16* const Bs = smem + 16384;

    if (bn == 12) {
        const int job = bm >> 4;           // 0:jkc 1:jvc
        const int r = bm & 15;
        const int bm2 = r >> 3, bn2 = r & 7;
        if (job == 0)
            gemm128p(As, As + 4096, hcm, WkT, kc_raw, nullptr, nullptr, 1.f, bm2, bn2, 1024, 1024);
        else
            gemm128p(As, As + 4096, hcm, WvT, vc_raw, nullptr, nullptr, 1.f, bm2, bn2, 1024, 1024);
        return;
    }

    const int lane = tid & 63, wv = tid >> 6;
    const int l15 = lane & 15, quad = lane >> 4;
    const int wm = (wv >> 2) * 128, wn = (wv & 3) * 64;

    f32x4 acc[8][4];
    #pragma unroll
    for (int i = 0; i < 8; ++i)
        #pragma unroll
        for (int j = 0; j < 4; ++j) acc[i][j] = (f32x4){0.f, 0.f, 0.f, 0.f};

    const int r_in = lane >> 2;
    const int col8 = (((lane & 3) ^ ((lane >> 3) & 3)) * 8);
    const bool isA = (wv < 4);
    const int crow0 = (isA ? wv : wv - 4) * 64;
    const u16* gb = isA ? (A + (long)(bm * 256 + crow0 + r_in) * K)
                        : (Bt + (long)(bn * 256 + crow0 + r_in) * K);
    const u16* s0 = gb + col8;
    const u16* s1 = s0 + (long)16 * K;
    const u16* s2 = s0 + (long)32 * K;
    const u16* s3 = s0 + (long)48 * K;
    u16* const lb = (isA ? As : Bs) + crow0 * 32;

    auto stage = [&](int buf) {
        u16* d = lb + buf * 8192;
        async16(s0, d);
        async16(s1, d + 512);
        async16(s2, d + 1024);
        async16(s3, d + 1536);
        s0 += 32; s1 += 32; s2 += 32; s3 += 32;
    };

    const int ssl = (quad ^ ((l15 >> 1) & 3)) * 8;   // swizzled read slot

    stage(0);
    for (int t = 0; t < NT; ++t) {
        __builtin_amdgcn_s_barrier();              // raw: WAR on buf[(t+1)&1]
        if (t + 1 < NT) {
            stage((t + 1) & 1);
            asm volatile("s_waitcnt vmcnt(4) lgkmcnt(0)\ns_barrier" ::: "memory");
        } else {
            asm volatile("s_waitcnt vmcnt(0) lgkmcnt(0)\ns_barrier" ::: "memory");
        }
        const u16* as = As + (t & 1) * 8192;
        const u16* bs = Bs + (t & 1) * 8192;
        short8 af[8], bfr[4];
        #pragma unroll
        for (int i = 0; i < 8; ++i)
            af[i] = *(const short8*)&as[(wm + i * 16 + l15) * 32 + ssl];
        #pragma unroll
        for (int j = 0; j < 4; ++j)
            bfr[j] = *(const short8*)&bs[(wn + j * 16 + l15) * 32 + ssl];
        #pragma unroll
        for (int i = 0; i < 8; ++i)
            #pragma unroll
            for (int j = 0; j < 4; ++j)
                acc[i][j] = __builtin_amdgcn_mfma_f32_16x16x32_bf16(af[i], bfr[j], acc[i][j], 0, 0, 0);
    }

    // ---- epilogue: two 128-row halves through LDS, coalesced stores ----
    const int mat = bn >> 2;                        // 0:q 1:k 2:v (uniform)
    u16* const outp = (mat == 0) ? q_ws : (mat == 1) ? kbp : vbp;
    const float scl = (mat == 0) ? 0.125f : 1.f;
    const int colbase = (bn & 3) * 256;
    #pragma unroll
    for (int hh = 0; hh < 2; ++hh) {
        __syncthreads();
        if ((wv >> 2) == hh) {
            #pragma unroll
            for (int i = 0; i < 8; ++i) {
                #pragma unroll
                for (int j = 0; j < 4; ++j) {
                    const int row = i * 16 + quad * 4;
                    const int col = wn + j * 16 + l15;
                    smem[(row + 0) * 256 + col] = f2bf(acc[i][j][0] * scl);
                    smem[(row + 1) * 256 + col] = f2bf(acc[i][j][1] * scl);
                    smem[(row + 2) * 256 + col] = f2bf(acc[i][j][2] * scl);
                    smem[(row + 3) * 256 + col] = f2bf(acc[i][j][3] * scl);
                }
            }
        }
        __syncthreads();
        #pragma unroll
        for (int k = 0; k < 8; ++k) {
            const int seg = tid + k * 512;
            const int row = seg >> 5, c16 = seg & 31;
            short8 v = *(const short8*)&smem[row * 256 + c16 * 8];
            *(short8*)(outp + (long)(bm * 256 + hh * 128 + row) * 1024 + colbase + c16 * 8) = v;
        }
    }
}

// ---------------------------------------------------------------------------
// Triple-buffered pipelined GEMM core (counted vmcnt, one barrier/iter),
// XOR-swizzled LDS. Tile 128x128, BK=32, K=1024 (NT=32), 4 waves.
// ---------------------------------------------------------------------------
#define GEMM_P3_BODY(EPILOGUE)                                                  \
    const int tid = threadIdx.x;                                                \
    const int bm = blockIdx.x, bn = blockIdx.y;                                 \
    const int K = 1024, NT = 32;                                                \
    __shared__ __align__(16) u16 As[3 * 128 * 32];                              \
    __shared__ __align__(16) u16 Bs[3 * 128 * 32];                              \
    const int lane = tid & 63, wv = tid >> 6;                                   \
    const int l15 = lane & 15, quad = lane >> 4;                                \
    const int wm = (wv & 1) * 64, wn = (wv >> 1) * 64;                          \
    f32x4 acc[4][4];                                                            \
    _Pragma("unroll")                                                           \
    for (int i = 0; i < 4; ++i)                                                 \
        _Pragma("unroll")                                                       \
        for (int j = 0; j < 4; ++j) acc[i][j] = (f32x4){0.f, 0.f, 0.f, 0.f};    \
    const int srow = wv * 32 + (lane >> 2);                                     \
    const int scol = (((lane & 3) ^ ((lane >> 3) & 3)) * 8);                    \
    const u16* a_src  = A  + (long)(bm * 128 + srow) * K + scol;                \
    const u16* a_src2 = a_src + (long)16 * K;                                   \
    const u16* b_src  = Bt + (long)(bn * 128 + srow) * K + scol;                \
    const u16* b_src2 = b_src + (long)16 * K;                                   \
    const int lofs0 = (wv * 32) * 32;                                           \
    const int lofs1 = (wv * 32 + 16) * 32;                                      \
    auto stage = [&](int t, int cur) {                                          \
        const int k0 = t * 32;                                                  \
        async16(a_src  + k0, &As[cur * 4096 + lofs0]);                          \
        async16(a_src2 + k0, &As[cur * 4096 + lofs1]);                          \
        async16(b_src  + k0, &Bs[cur * 4096 + lofs0]);                          \
        async16(b_src2 + k0, &Bs[cur * 4096 + lofs1]);                          \
    };                                                                          \
    stage(0, 0); stage(1, 1);                                                   \
    const int ssl = (quad ^ ((l15 >> 1) & 3)) * 8;                              \
    int cur = 0;                                                                \
    for (int t = 0; t < NT; ++t) {                                              \
        if (t == NT - 1)                                                        \
            asm volatile("s_waitcnt vmcnt(0) lgkmcnt(0)\ns_barrier" ::: "memory"); \
        else                                                                    \
            asm volatile("s_waitcnt vmcnt(4) lgkmcnt(0)\ns_barrier" ::: "memory"); \
        int nxt = cur + 2; if (nxt >= 3) nxt -= 3;                              \
        if (t + 2 < NT) stage(t + 2, nxt);                                      \
        const u16* as = &As[cur * 4096];                                        \
        const u16* bs = &Bs[cur * 4096];                                        \
        short8 af[4], bfr[4];                                                   \
        _Pragma("unroll")                                                       \
        for (int i = 0; i < 4; ++i)                                             \
            af[i] = *(const short8*)&as[(wm + i * 16 + l15) * 32 + ssl];        \
        _Pragma("unroll")                                                       \
        for (int j = 0; j < 4; ++j)                                             \
            bfr[j] = *(const short8*)&bs[(wn + j * 16 + l15) * 32 + ssl];       \
        _Pragma("unroll")                                                       \
        for (int i = 0; i < 4; ++i)                                             \
            _Pragma("unroll")                                                   \
            for (int j = 0; j < 4; ++j)                                         \
                acc[i][j] = __builtin_amdgcn_mfma_f32_16x16x32_bf16(af[i], bfr[j], acc[i][j], 0, 0, 0); \
        cur = (cur + 1 == 3) ? 0 : cur + 1;                                     \
    }                                                                           \
    EPILOGUE

// Output projection: A (8192x1024 bf16) @ WoT^T -> f32. grid=(64,8).
__global__ __launch_bounds__(256) void gemm_out3(
    const u16* __restrict__ A, const u16* __restrict__ Bt,
    float* __restrict__ Cf)
{
    GEMM_P3_BODY({
        _Pragma("unroll")
        for (int i = 0; i < 4; ++i) {
            _Pragma("unroll")
            for (int j = 0; j < 4; ++j) {
                int col = bn * 128 + wn + j * 16 + l15;
                _Pragma("unroll")
                for (int r = 0; r < 4; ++r) {
                    int row = bm * 128 + wm + i * 16 + quad * 4 + r;
                    Cf[(long)row * 1024 + col] = acc[i][j][r];
                }
            }
        }
    })
}

// ---------------------------------------------------------------------------
// Post-QKV fused kernel. flat grid = 8704 + 512 = 9216.
// ---------------------------------------------------------------------------
__global__ __launch_bounds__(256) void post_qkv(
    const float* __restrict__ kcw, const float* __restrict__ vcw,
    const u16* __restrict__ kbp, const u16* __restrict__ vbp,
    float2* __restrict__ st_k, float2* __restrict__ st_v,
    const float* __restrict__ sc,
    const float* __restrict__ kc, const float* __restrict__ vc,
    const float* __restrict__ g, const float* __restrict__ be,
    u16* __restrict__ k_comp, u16* __restrict__ vcT)
{
    const int gr = blockIdx.x;
    const int tid = threadIdx.x;
    const int lane = tid & 63, wv = tid >> 6;

    if (gr < 8704) {
        float sm1 = 0.f, sq1 = 0.f, sm2 = 0.f, sq2 = 0.f;
        long dst;
        if (gr < 512) {
            const int b = gr >> 7, r = gr & 127;
            const float* p1 = kcw + ((long)b * 128 + r) * 1024;
            const float* p2 = vcw + ((long)b * 128 + r) * 1024;
            #pragma unroll
            for (int p = 0; p < 4; ++p) {
                float x = p1[tid + p * 256];
                float y = p2[tid + p * 256];
                sm1 += x; sq1 += x * x;
                sm2 += y; sq2 += y * y;
            }
            dst = (long)b * 2176 + r;
        } else {
            const int g2 = gr - 512;
            const int b = g2 >> 11, r = g2 & 2047;
            const u16* p1 = kbp + ((long)b * 2048 + r) * 1024 + tid * 4;
            const u16* p2 = vbp + ((long)b * 2048 + r) * 1024 + tid * 4;
            uint2 v1 = *(const uint2*)p1;
            uint2 v2 = *(const uint2*)p2;
            const u16* a1 = (const u16*)&v1;
            const u16* a2 = (const u16*)&v2;
            #pragma unroll
            for (int p = 0; p < 4; ++p) {
                float x = bf2f(a1[p]);
                float y = bf2f(a2[p]);
                sm1 += x; sq1 += x * x;
                sm2 += y; sq2 += y * y;
            }
            dst = (long)b * 2176 + 128 + r;
        }

        __shared__ float red[4][4];
        for (int off = 32; off; off >>= 1) {
            sm1 += __shfl_xor(sm1, off); sq1 += __shfl_xor(sq1, off);
            sm2 += __shfl_xor(sm2, off); sq2 += __shfl_xor(sq2, off);
        }
        if (lane == 0) { red[0][wv] = sm1; red[1][wv] = sq1; red[2][wv] = sm2; red[3][wv] = sq2; }
        __syncthreads();
        if (tid == 0) {
            sm1 = red[0][0] + red[0][1] + red[0][2] + red[0][3];
            sq1 = red[1][0] + red[1][1] + red[1][2] + red[1][3];
            sm2 = red[2][0] + red[2][1] + red[2][2] + red[2][3];
            sq2 = red[3][0] + red[3][1] + red[3][2] + red[3][3];
            float m1 = sm1 * (1.f / 1024.f);
            float i1 = rsqrtf(fmaxf(sq1 * (1.f / 1024.f) - m1 * m1, 0.f) + 1e-5f);
            float m2 = sm2 * (1.f / 1024.f);
            float i2 = rsqrtf(fmaxf(sq2 * (1.f / 1024.f) - m2 * m2, 0.f) + 1e-5f);
            st_k[dst] = make_float2(m1, i1);
            st_v[dst] = make_float2(m2, i2);
        }
        return;
    }

    const int idx = gr - 8704;                 // 0..511
    const int zz = idx >> 8;                   // 0..1
    const int b = (idx >> 6) & 3;
    const int cx = idx & 63;

    if (zz == 0) {
        const int c = cx;
        __shared__ float scw[16][32];
        __shared__ float red[4][4];

        for (int i2 = tid; i2 < 512; i2 += 256) {
            int hd = i2 >> 5, i = i2 & 31;
            scw[hd][i] = sc[((long)(b * 16 + hd) * 64 + c) * 32 + i];
        }
        __syncthreads();

        const int j0 = tid * 4;
        const int hd = j0 >> 6;
        float xk[4] = {0.f,0.f,0.f,0.f}, xv[4] = {0.f,0.f,0.f,0.f};
        const u16* kb = kbp + ((long)b * 2048 + c * 32) * 1024 + j0;
        const u16* vb = vbp + ((long)b * 2048 + c * 32) * 1024 + j0;
        for (int i = 0; i < 32; ++i) {
            float w = scw[hd][i];
            uint2 kr = *(const uint2*)(kb + (long)i * 1024);
            uint2 vr = *(const uint2*)(vb + (long)i * 1024);
            const u16* kp = (const u16*)&kr;
            const u16* vp = (const u16*)&vr;
            #pragma unroll
            for (int p = 0; p < 4; ++p) {
                xk[p] += w * bf2f(kp[p]);
                xv[p] += w * bf2f(vp[p]);
            }
        }
        float sk = 0.f, qk = 0.f, sv = 0.f, qv = 0.f;
        #pragma unroll
        for (int p = 0; p < 4; ++p) { sk += xk[p]; qk += xk[p]*xk[p]; sv += xv[p]; qv += xv[p]*xv[p]; }
        for (int off = 32; off; off >>= 1) {
            sk += __shfl_xor(sk, off); qk += __shfl_xor(qk, off);
            sv += __shfl_xor(sv, off); qv += __shfl_xor(qv, off);
        }
        if (lane == 0) { red[0][wv] = sk; red[1][wv] = qk; red[2][wv] = sv; red[3][wv] = qv; }
        __syncthreads();
        sk = red[0][0] + red[0][1] + red[0][2] + red[0][3];
        qk = red[1][0] + red[1][1] + red[1][2] + red[1][3];
        sv = red[2][0] + red[2][1] + red[2][2] + red[2][3];
        qv = red[3][0] + red[3][1] + red[3][2] + red[3][3];
        const float inv_n = 1.f / 1024.f;
        float mk = sk * inv_n, mv = sv * inv_n;
        float ik = rsqrtf(fmaxf(qk * inv_n - mk * mk, 0.f) + 1e-5f);
        float iv = rsqrtf(fmaxf(qv * inv_n - mv * mv, 0.f) + 1e-5f);
        float4 g4 = *(const float4*)(g + j0);
        float4 b4 = *(const float4*)(be + j0);
        float gg[4] = {g4.x, g4.y, g4.z, g4.w};
        float bb[4] = {b4.x, b4.y, b4.z, b4.w};
        u16 ko[4];
        #pragma unroll
        for (int p = 0; p < 4; ++p) ko[p] = f2bf((xk[p] - mk) * ik * gg[p] + bb[p]);
        *(uint2*)&k_comp[((long)b * 128 + 64 + c) * 1024 + j0] = *(const uint2*)ko;
        #pragma unroll
        for (int p = 0; p < 4; ++p)
            vcT[((long)b * 1024 + j0 + p) * 128 + 64 + c] = f2bf((xv[p] - mv) * iv * gg[p] + bb[p]);
    } else {
        const int r = cx;
        const float* pk = kc + ((long)b * 64 + r) * 1024;
        const float* pv = vc + ((long)b * 64 + r) * 1024;

        __shared__ float red2[4][4];
        float xk[4], xv[4];
        float smk = 0.f, sqk = 0.f, smv = 0.f, sqv = 0.f;
        #pragma unroll
        for (int p = 0; p < 4; ++p) {
            xk[p] = pk[tid + p * 256];
            xv[p] = pv[tid + p * 256];
            smk += xk[p]; sqk += xk[p] * xk[p];
            smv += xv[p]; sqv += xv[p] * xv[p];
        }
        for (int off = 32; off; off >>= 1) {
            smk += __shfl_xor(smk, off); sqk += __shfl_xor(sqk, off);
            smv += __shfl_xor(smv, off); sqv += __shfl_xor(sqv, off);
        }
        if (lane == 0) { red2[0][wv] = smk; red2[1][wv] = sqk; red2[2][wv] = smv; red2[3][wv] = sqv; }
        __syncthreads();
        smk = red2[0][0] + red2[0][1] + red2[0][2] + red2[0][3];
        sqk = red2[1][0] + red2[1][1] + red2[1][2] + red2[1][3];
        smv = red2[2][0] + red2[2][1] + red2[2][2] + red2[2][3];
        sqv = red2[3][0] + red2[3][1] + red2[3][2] + red2[3][3];
        const float inv_n = 1.f / 1024.f;
        float mk = smk * inv_n, mv = smv * inv_n;
        float ik = rsqrtf(fmaxf(sqk * inv_n - mk * mk, 0.f) + 1e-5f);
        float iv = rsqrtf(fmaxf(sqv * inv_n - mv * mv, 0.f) + 1e-5f);
        #pragma unroll
        for (int p = 0; p < 4; ++p) {
            int j = tid + p * 256;
            k_comp[((long)b * 128 + r) * 1024 + j] = f2bf((xk[p] - mk) * ik * g[j] + be[j]);
            vcT[((long)b * 1024 + j) * 128 + r]    = f2bf((xv[p] - mv) * iv * g[j] + be[j]);
        }
    }
}

// ---------------------------------------------------------------------------
// Materialize window K (bf16 (B,2176,1024)) and V^T (bf16 (B,1024,2176),
// col = concat_row - 1).  grid=(34, 16, B). kbp/vbp are bf16.
// ---------------------------------------------------------------------------
__global__ __launch_bounds__(256) void win_apply(
    const float* __restrict__ kcw, const float* __restrict__ vcw,
    const u16* __restrict__ kbp, const u16* __restrict__ vbp,
    const float2* __restrict__ st_kw, const float2* __restrict__ st_vw,
    const float* __restrict__ g_w, const float* __restrict__ b_w,
    u16* __restrict__ kwin, u16* __restrict__ vwinT)
{
    const int tt = blockIdx.x, dc = blockIdx.y, b = blockIdx.z;
    const int t0 = tt * 64, d0 = dc * 64;
    const int tid = threadIdx.x;

    __shared__ u16 vt[64][74];

    const int r = tid >> 2;
    const int dsub = (tid & 3) * 16;
    const int t = t0 + r;
    float2 sk = st_kw[(long)b * 2176 + t];
    float2 sv = st_vw[(long)b * 2176 + t];
    const float* ksf = kcw + ((long)b * 128 + t) * 1024;
    const float* vsf = vcw + ((long)b * 128 + t) * 1024;
    const u16*   ksb = kbp + ((long)b * 2048 + t - 128) * 1024;
    const u16*   vsb = vbp + ((long)b * 2048 + t - 128) * 1024;
    #pragma unroll
    for (int j = 0; j < 16; j += 4) {
        int d = d0 + dsub + j;
        float4 kv, vv;
        if (t < 128) {
            kv = *(const float4*)(ksf + d);
            vv = *(const float4*)(vsf + d);
        } else {
            uint2 kr = *(const uint2*)(ksb + d);
            uint2 vr = *(const uint2*)(vsb + d);
            const u16* kp = (const u16*)&kr;
            const u16* vp = (const u16*)&vr;
            kv = make_float4(bf2f(kp[0]), bf2f(kp[1]), bf2f(kp[2]), bf2f(kp[3]));
            vv = make_float4(bf2f(vp[0]), bf2f(vp[1]), bf2f(vp[2]), bf2f(vp[3]));
        }
        float4 g4 = *(const float4*)(g_w + d);
        float4 b4 = *(const float4*)(b_w + d);
        u16 ko[4];
        ko[0] = f2bf((kv.x - sk.x) * sk.y * g4.x + b4.x);
        ko[1] = f2bf((kv.y - sk.x) * sk.y * g4.y + b4.y);
        ko[2] = f2bf((kv.z - sk.x) * sk.y * g4.z + b4.z);
        ko[3] = f2bf((kv.w - sk.x) * sk.y * g4.w + b4.w);
        *(uint2*)&kwin[((long)b * 2176 + t) * 1024 + d] = *(const uint2*)ko;
        vt[r][dsub + j + 0] = f2bf((vv.x - sv.x) * sv.y * g4.x + b4.x);
        vt[r][dsub + j + 1] = f2bf((vv.y - sv.x) * sv.y * g4.y + b4.y);
        vt[r][dsub + j + 2] = f2bf((vv.z - sv.x) * sv.y * g4.z + b4.z);
        vt[r][dsub + j + 3] = f2bf((vv.w - sv.x) * sv.y * g4.w + b4.w);
    }
    __syncthreads();
    #pragma unroll
    for (int pass = 0; pass < 16; ++pass) {
        int dd = (tid >> 6) + pass * 4;
        int rr = tid & 63;
        int crow = t0 + rr;
        if (crow >= 1)
            vwinT[((long)b * 1024 + d0 + dd) * 2176 + crow - 1] = vt[rr][dd];
    }
}

// ---------------------------------------------------------------------------
// Fused MFMA attention: one block per (h, qc, b), 256 thr = 4 waves.
// Grid x = h (fastest) so 16 consecutive blocks share kwb/vwT rows -> L2.
// LDS = L (32x260 f32) + qa (32x72 bf16) = 37.9 KB -> 4 blocks/CU.
// S1 k_win rows AND S_c kcb/pcb operands prefetched into regs BEFORE the
// q barrier (issue-early); PV B-operands prefetched before softmax.
// ---------------------------------------------------------------------------
__global__ __launch_bounds__(256, 4) void attention(
    const u16* __restrict__ qb,     // (B,2048,1024) bf16, already /8
    const u16* __restrict__ kcb,    // (B,128,1024) bf16
    const u16* __restrict__ vcT,    // (B,1024,128) bf16 transposed
    const u16* __restrict__ kwb,    // (B,2176,1024) bf16
    const u16* __restrict__ vwT,    // (B,1024,2176) bf16 transposed, col=row-1
    const u16* __restrict__ pcb,    // (128,1024) bf16
    const u16* __restrict__ ptb,    // (128,1024) bf16
    const float* __restrict__ r_w,  // (16,64)
    const float* __restrict__ r_r,
    u16* __restrict__ attn_o)       // (B,2048,1024) bf16
{
    const int h = blockIdx.x, qc = blockIdx.y, b = blockIdx.z;
    const int l0 = qc * 32;
    const int tid = threadIdx.x;
    const int lane = tid & 63, wv = tid >> 6;
    const int l15 = lane & 15, quad = lane >> 4;

    __shared__ __align__(16) float L[32 * 260];     // logits; P aliases row tails
    __shared__ __align__(16) u16 qa[32][72];        // plain q (bf16)
    u16* Lu = (u16*)L;                              // row stride 520 u16

    // ---- stage q ----
    {
        const int r = tid >> 3, d0 = (tid & 7) * 8;
        short8 qv = ldg8(qb + ((long)(b * 2048 + l0 + r)) * 1024 + h * 64 + d0);
        *(short8*)&qa[r][d0] = qv;
    }

    // ---- prefetch S1 k_win rows + S_c kcb/pcb operands (pre-barrier) ----
    short8 s1k[3][2];
    int nw = 0;
    #pragma unroll
    for (int i = 0; i < 3; ++i) {
        const int nt = wv + i * 4;
        if (nt < 10) {
            int t = nt * 16 + l15;
            int row = l0 + 1 + t; if (row > 2175) row = 2175;
            const u16* kp = kwb + ((long)(b * 2176 + row)) * 1024 + h * 64 + quad * 8;
            s1k[i][0] = ldg8(kp);
            s1k[i][1] = ldg8(kp + 32);
            nw = i + 1;
        }
    }
    short8 sck[2][2], scp[2][2];
    #pragma unroll
    for (int ti = 0; ti < 2; ++ti) {
        const int ci = (wv * 2 + ti) * 16 + l15;
        int p = 64 + ci - qc; if (p > 127) p = 127;
        const u16* kp2 = kcb + ((long)(b * 128 + ci)) * 1024 + h * 64 + quad * 8;
        const u16* pp2 = pcb + (long)p * 1024 + h * 64 + quad * 8;
        sck[ti][0] = ldg8(kp2); sck[ti][1] = ldg8(kp2 + 32);
        scp[ti][0] = ldg8(pp2); scp[ti][1] = ldg8(pp2 + 32);
    }
    __syncthreads();

    __builtin_amdgcn_s_setprio(1);
    // ---- S_c: q·k_comp + q·pos_c[64+ci-qc], tiles 2wv..2wv+1 (regs) ----
    #pragma unroll
    for (int ti = 0; ti < 2; ++ti) {
        int n0 = (wv * 2 + ti) * 16;
        int ci = n0 + l15;
        f32x4 a0 = {0.f,0.f,0.f,0.f}, a1 = {0.f,0.f,0.f,0.f};
        if (n0 < 64 + qc) {
            #pragma unroll
            for (int kc = 0; kc < 2; ++kc) {
                int k0 = kc * 32;
                short8 fa0 = *(const short8*)&qa[l15][k0 + quad * 8];
                short8 fa1 = *(const short8*)&qa[16 + l15][k0 + quad * 8];
                a0 = __builtin_amdgcn_mfma_f32_16x16x32_bf16(fa0, sck[ti][kc], a0, 0, 0, 0);
                a0 = __builtin_amdgcn_mfma_f32_16x16x32_bf16(fa0, scp[ti][kc], a0, 0, 0, 0);
                a1 = __builtin_amdgcn_mfma_f32_16x16x32_bf16(fa1, sck[ti][kc], a1, 0, 0, 0);
                a1 = __builtin_amdgcn_mfma_f32_16x16x32_bf16(fa1, scp[ti][kc], a1, 0, 0, 0);
            }
        }
        bool msk = (ci >= 64 + qc);
        #pragma unroll
        for (int r = 0; r < 4; ++r) {
            L[(quad * 4 + r) * 260 + ci]      = msk ? NEGINF : a0[r];
            L[(16 + quad * 4 + r) * 260 + ci] = msk ? NEGINF : a1[r];
        }
    }

    // ---- S2: (q+r_r)·pos_t; biased frags built in registers ----
    {
        short8 qf[2][2];
        #pragma unroll
        for (int kc = 0; kc < 2; ++kc) {
            const int off = kc * 32 + quad * 8;
            const float* bp_ = r_r + h * 64 + off;
            float4 b0 = *(const float4*)bp_;
            float4 b1 = *(const float4*)(bp_ + 4);
            float bb[8] = {b0.x,b0.y,b0.z,b0.w,b1.x,b1.y,b1.z,b1.w};
            #pragma unroll
            for (int hf = 0; hf < 2; ++hf) {
                short8 qv = *(const short8*)&qa[hf * 16 + l15][off];
                short8 f;
                #pragma unroll
                for (int j = 0; j < 8; ++j) f[j] = (short)f2bf(bf2f((u16)qv[j]) + bb[j]);
                qf[kc][hf] = f;
            }
        }
        #pragma unroll
        for (int ti = 0; ti < 2; ++ti) {
            int w0 = (wv * 2 + ti) * 16;
            int w = w0 + l15;
            f32x4 a0 = {0.f,0.f,0.f,0.f}, a1 = {0.f,0.f,0.f,0.f};
            #pragma unroll
            for (int kc = 0; kc < 2; ++kc) {
                int k0 = kc * 32;
                short8 bp = ldg8(ptb + (long)w * 1024 + h * 64 + k0 + quad * 8);
                a0 = __builtin_amdgcn_mfma_f32_16x16x32_bf16(qf[kc][0], bp, a0, 0, 0, 0);
                a1 = __builtin_amdgcn_mfma_f32_16x16x32_bf16(qf[kc][1], bp, a1, 0, 0, 0);
            }
            #pragma unroll
            for (int r = 0; r < 4; ++r) {
                L[(quad * 4 + r) * 260 + 128 + w]      = a0[r];
                L[(16 + quad * 4 + r) * 260 + 128 + w] = a1[r];
            }
        }
    }

    // ---- S1: (q+r_w)·k_win MFMAs from prefetched regs ----
    f32x4 s1a[3], s1b[3];
    {
        short8 qf[2][2];
        #pragma unroll
        for (int kc = 0; kc < 2; ++kc) {
            const int off = kc * 32 + quad * 8;
            const float* bp_ = r_w + h * 64 + off;
            float4 b0 = *(const float4*)bp_;
            float4 b1 = *(const float4*)(bp_ + 4);
            float bb[8] = {b0.x,b0.y,b0.z,b0.w,b1.x,b1.y,b1.z,b1.w};
            #pragma unroll
            for (int hf = 0; hf < 2; ++hf) {
                short8 qv = *(const short8*)&qa[hf * 16 + l15][off];
                short8 f;
                #pragma unroll
                for (int j = 0; j < 8; ++j) f[j] = (short)f2bf(bf2f((u16)qv[j]) + bb[j]);
                qf[kc][hf] = f;
            }
        }
        #pragma unroll
        for (int i = 0; i < 3; ++i) {
            if (i < nw) {
                f32x4 a0 = {0.f,0.f,0.f,0.f}, a1 = {0.f,0.f,0.f,0.f};
                #pragma unroll
                for (int kc = 0; kc < 2; ++kc) {
                    a0 = __builtin_amdgcn_mfma_f32_16x16x32_bf16(qf[kc][0], s1k[i][kc], a0, 0, 0, 0);
                    a1 = __builtin_amdgcn_mfma_f32_16x16x32_bf16(qf[kc][1], s1k[i][kc], a1, 0, 0, 0);
                }
                s1a[i] = a0; s1b[i] = a1;
            }
        }
    }
    __builtin_amdgcn_s_setprio(0);
    __syncthreads();
    // band add: L[row][128 + (t-row)] += S1
    #pragma unroll
    for (int i = 0; i < 3; ++i) {
        if (i < nw) {
            int t = (wv + i * 4) * 16 + l15;
            #pragma unroll
            for (int r = 0; r < 4; ++r) {
                int r0 = quad * 4 + r;
                int w0 = t - r0;
                if (w0 >= 0 && w0 < 128) L[r0 * 260 + 128 + w0] += s1a[i][r];
                int r1 = 16 + quad * 4 + r;
                int w1 = t - r1;
                if (w1 >= 0 && w1 < 128) L[r1 * 260 + 128 + w1] += s1b[i][r];
            }
        }
    }
    __syncthreads();

    // ---- prefetch PV B-operands into registers (hide latency under softmax)
    const int n0d = wv * 16;
    short8 bvv[9];
    {
        const u16* vc = vcT + ((long)(b * 1024 + h * 64 + n0d + l15)) * 128 + quad * 8;
        #pragma unroll
        for (int kc = 0; kc < 4; ++kc) bvv[kc] = ldg8(vc + kc * 32);
        const u16* vw = vwT + ((long)(b * 1024 + h * 64 + n0d + l15)) * 2176 + l0 + quad * 8;
        #pragma unroll
        for (int kc = 0; kc < 5; ++kc) bvv[4 + kc] = ldg8(vw + kc * 32);
    }

    // ---- softmax: wave wv owns rows wv*8..wv*8+7; lane holds cols 4l..4l+3.
    #pragma unroll
    for (int rr = 0; rr < 8; ++rr) {
        const int r = wv * 8 + rr;
        float4 v = *(const float4*)&L[r * 260 + lane * 4];
        float m = fmaxf(fmaxf(v.x, v.y), fmaxf(v.z, v.w));
        for (int off = 32; off; off >>= 1) m = fmaxf(m, __shfl_xor(m, off));
        float e0 = __expf(v.x - m), e1 = __expf(v.y - m);
        float e2 = __expf(v.z - m), e3 = __expf(v.w - m);
        float s = (e0 + e1) + (e2 + e3);
        for (int off = 32; off; off >>= 1) s += __shfl_xor(s, off);
        float inv = 1.f / s;
        e0 *= inv; e1 *= inv; e2 *= inv; e3 *= inv;
        u16* rowP = Lu + (long)r * 520;
        if (lane < 32) {
            u16 pk[4] = {f2bf(e0), f2bf(e1), f2bf(e2), f2bf(e3)};
            *(uint2*)&rowP[lane * 4] = *(const uint2*)pk;
        } else {
            const int l = lane - 32;          // 0..31
            const int t = 4 * l + r;          // band: t = w + r
            u16* p = rowP + 160 + t;
            p[0] = f2bf(e0); p[1] = f2bf(e1); p[2] = f2bf(e2); p[3] = f2bf(e3);
            const int tz = (l < r) ? l : 128 + l;
            rowP[160 + tz] = 0;
        }
    }
    __syncthreads();

    // ---- PV: wave wv -> d-tile wv*16 (B-operands already in registers) ----
    __builtin_amdgcn_s_setprio(1);
    f32x4 o0 = {0.f,0.f,0.f,0.f}, o1 = {0.f,0.f,0.f,0.f};
    #pragma unroll
    for (int kc = 0; kc < 4; ++kc) {           // compressed, K=128
        int k0 = kc * 32;
        short8 av0 = *(const short8*)(Lu + (long)l15 * 520 + k0 + quad * 8);
        short8 av1 = *(const short8*)(Lu + (long)(16 + l15) * 520 + k0 + quad * 8);
        o0 = __builtin_amdgcn_mfma_f32_16x16x32_bf16(av0, bvv[kc], o0, 0, 0, 0);
        o1 = __builtin_amdgcn_mfma_f32_16x16x32_bf16(av1, bvv[kc], o1, 0, 0, 0);
    }
    #pragma unroll
    for (int kc = 0; kc < 5; ++kc) {           // windowed, K=160 banded
        int k0 = kc * 32;
        short8 av0 = *(const short8*)(Lu + (long)l15 * 520 + 160 + k0 + quad * 8);
        short8 av1 = *(const short8*)(Lu + (long)(16 + l15) * 520 + 160 + k0 + quad * 8);
        o0 = __builtin_amdgcn_mfma_f32_16x16x32_bf16(av0, bvv[4 + kc], o0, 0, 0, 0);
        o1 = __builtin_amdgcn_mfma_f32_16x16x32_bf16(av1, bvv[4 + kc], o1, 0, 0, 0);
    }
    __builtin_amdgcn_s_setprio(0);
    #pragma unroll
    for (int r = 0; r < 4; ++r) {
        int r0 = quad * 4 + r, r1 = 16 + quad * 4 + r;
        attn_o[((long)(b * 2048 + l0 + r0)) * 1024 + h * 64 + n0d + l15] = f2bf(o0[r]);
        attn_o[((long)(b * 2048 + l0 + r1)) * 1024 + h * 64 + n0d + l15] = f2bf(o1[r]);
    }
}

// ---------------------------------------------------------------------------
extern "C" void kernel_launch(void* const* d_in, const int* in_sizes, int n_in,
                              void* d_out, int out_size, void* d_ws, size_t ws_size,
                              hipStream_t stream)
{
    (void)in_sizes; (void)n_in; (void)out_size; (void)ws_size;

    const float* h       = (const float*)d_in[0];
    const float* h_cache = (const float*)d_in[1];
    const float* key_pe  = (const float*)d_in[2];
    const float* pos_w   = (const float*)d_in[3];
    const float* Wq      = (const float*)d_in[4];
    const float* Wk      = (const float*)d_in[5];
    const float* Wv      = (const float*)d_in[6];
    const float* Wo      = (const float*)d_in[7];
    const float* Wd      = (const float*)d_in[8];
    const float* bd      = (const float*)d_in[9];
    const float* Wr      = (const float*)d_in[10];
    const float* br      = (const float*)d_in[11];
    const float* Wrc     = (const float*)d_in[12];
    const float* brc     = (const float*)d_in[13];
    const float* r_r     = (const float*)d_in[14];
    const float* r_w     = (const float*)d_in[15];
    const float* g_d     = (const float*)d_in[16];
    const float* b_d     = (const float*)d_in[17];
    const float* g_w     = (const float*)d_in[18];
    const float* b_w     = (const float*)d_in[19];

    char* ws = (char*)d_ws;
    size_t off = 0;
    auto alloc = [&](size_t bytes) -> void* {
        void* p = ws + off; off += (bytes + 255) & ~(size_t)255; return p;
    };
    // bf16 casts / transposed weights (N,K)
    u16* hB     = (u16*)alloc((size_t)8192 * 1024 * 2);
    u16* hcwB   = (u16*)alloc((size_t)4 * 128 * 1024 * 2);
    u16* WqkvT  = (u16*)alloc((size_t)3 * 1024 * 1024 * 2);   // Wq|Wk|Wv stacked
    u16* WoT    = (u16*)alloc((size_t)1024 * 1024 * 2);
    u16* WrT    = (u16*)alloc((size_t)1024 * 1024 * 2);
    u16* WrcT   = (u16*)alloc((size_t)1024 * 1024 * 2);
    u16* pwB    = (u16*)alloc((size_t)128 * 1024 * 2);
    u16* kpeB   = (u16*)alloc((size_t)128 * 1024 * 2);
    u16* WdB    = (u16*)alloc((size_t)16 * 1024 * 2);
    // intermediates
    u16*   q_ws   = (u16*)alloc((size_t)8192 * 1024 * 2);
    u16*   kbp    = (u16*)alloc((size_t)8192 * 1024 * 2);     // bf16
    u16*   vbp    = (u16*)alloc((size_t)8192 * 1024 * 2);     // bf16
    u16*   attn_o = (u16*)alloc((size_t)8192 * 1024 * 2);
    float* kcw    = (float*)alloc((size_t)4 * 128 * 1024 * 4);
    float* vcw    = (float*)alloc((size_t)4 * 128 * 1024 * 4);
    u16*   hcm    = (u16*)alloc((size_t)4 * 64 * 1024 * 2);
    float* kc_raw = (float*)alloc((size_t)4 * 64 * 1024 * 4);
    float* vc_raw = (float*)alloc((size_t)4 * 64 * 1024 * 4);
    float* sc_blk = (float*)alloc((size_t)4 * 16 * 64 * 32 * 4);
    u16*   k_comp = (u16*)alloc((size_t)4 * 128 * 1024 * 2);
    u16*   vcT    = (u16*)alloc((size_t)4 * 1024 * 128 * 2);
    float2* st_kw = (float2*)alloc((size_t)4 * 2176 * 8);
    float2* st_vw = (float2*)alloc((size_t)4 * 2176 * 8);
    u16*   pos_tb = (u16*)alloc((size_t)128 * 1024 * 2);
    u16*   pos_cb = (u16*)alloc((size_t)128 * 1024 * 2);
    u16*   kwin   = (u16*)alloc((size_t)4 * 2176 * 1024 * 2);
    u16*   vwinT  = (u16*)alloc((size_t)4 * 1024 * 2176 * 2 + 256);

    const u16* WkT = WqkvT + (size_t)1024 * 1024;
    const u16* WvT = WqkvT + (size_t)2 * 1024 * 1024;

    const dim3 blk(256);

    // all casts + weight transposes in ONE launch
    cast_fuse<<<dim3(15168), blk, 0, stream>>>(
        h, h_cache, pos_w, key_pe, Wd, hB, hcwB, pwB, kpeB, WdB,
        Wq, Wk, Wv, Wo, Wr, Wrc,
        WqkvT, WqkvT + (size_t)1024*1024, WqkvT + (size_t)2*1024*1024,
        WoT, WrT, WrcT);

    // scores/compress + the four independent small GEMMs, ONE launch
    scores_multi<<<dim3(64,8,3), blk, 0, stream>>>(
        h_cache, hB, WdB, bd, hcm, sc_blk,
        hcwB, WkT, WvT, kcw, vcw,
        pwB, WrT, pos_tb, br,
        kpeB, WrcT, pos_cb, brc);

    // fused QKV projection (+ the two hcm-dependent 128^2 GEMMs at bn=12)
    gemm_qkv_big<<<dim3(32,13), dim3(512), 0, stream>>>(hB, WqkvT, q_ws, kbp, vbp,
                                                        hcm, WkT, WvT, kc_raw, vc_raw);

    // window-LN stats + compress+LN for k_comp/vcT, ONE launch (9216 blocks)
    post_qkv<<<dim3(9216), blk, 0, stream>>>(kcw, vcw, kbp, vbp, st_kw, st_vw,
                                             sc_blk, kc_raw, vc_raw, g_d, b_d,
                                             k_comp, vcT);

    win_apply<<<dim3(34,16,4), blk, 0, stream>>>(kcw, vcw, kbp, vbp, st_kw, st_vw, g_w, b_w, kwin, vwinT);

    // attention (grid: h fastest for kwb/vwT L2 sharing)
    attention<<<dim3(16,64,4), blk, 0, stream>>>(q_ws, k_comp, vcT, kwin, vwinT,
                                                 pos_cb, pos_tb, r_w, r_r, attn_o);
    // output projection, pipelined
    gemm_out3<<<dim3(64,8,1), blk, 0, stream>>>(attn_o, WoT, (float*)d_out);
}

// Round 11
// 422.843 us; speedup vs baseline: 1.0390x; 1.0390x over previous
//
#include <hip/hip_runtime.h>

// ChunkedLSAttention on MI355X (gfx950).
// B=4, L=2048, D=1024, H=16, DH=64, W=128, CS=32, NCC=NCB=64, NC=128, NQ=64.
// All inputs/outputs f32. bf16 for all MFMA operands (f32 accumulate).
// kbp/vbp stored bf16. Mask: masked iff ci-64 >= qc.
// GEMM LDS tiles XOR bank-swizzled (pre-swizzled global src + swizzled read).
// Attention grid (h, qc, b): h fastest -> 16 consecutive blocks share kwb/vwT
// rows (adjacent 128B column slices) -> full L2-line consumption.

typedef unsigned short u16;
typedef __attribute__((ext_vector_type(8))) short short8;
typedef __attribute__((ext_vector_type(4))) float f32x4;

#define NEGINF -1e30f

__device__ __forceinline__ float bf2f(u16 u) {
    union { unsigned int i; float f; } v; v.i = ((unsigned int)u) << 16; return v.f;
}
__device__ __forceinline__ u16 f2bf(float f) {
    union { float fl; unsigned int i; } v; v.fl = f;
    unsigned int x = v.i;
    return (u16)((x + 0x7fffu + ((x >> 16) & 1u)) >> 16);   // RNE
}
__device__ __forceinline__ short8 ldg8(const u16* p) { return *(const short8*)p; }

// async global->LDS, 16B per lane; LDS dest = wave-uniform base + lane*16.
__device__ __forceinline__ void async16(const u16* g, u16* l) {
    __builtin_amdgcn_global_load_lds(
        (const __attribute__((address_space(1))) unsigned int*)g,
        (__attribute__((address_space(3))) unsigned int*)l, 16, 0, 0);
}

// ---------------------------------------------------------------------------
// All casts + six weight transposes in ONE launch. grid = 15168.
// ---------------------------------------------------------------------------
__global__ __launch_bounds__(256) void cast_fuse(
    const float* __restrict__ h, const float* __restrict__ hc,
    const float* __restrict__ pos_w, const float* __restrict__ key_pe,
    const float* __restrict__ Wd,
    u16* __restrict__ hB, u16* __restrict__ hcwB,
    u16* __restrict__ pwB, u16* __restrict__ kpeB, u16* __restrict__ WdB,
    const float* __restrict__ W0, const float* __restrict__ W1,
    const float* __restrict__ W2, const float* __restrict__ W3,
    const float* __restrict__ W4, const float* __restrict__ W5,
    u16* __restrict__ D0, u16* __restrict__ D1, u16* __restrict__ D2,
    u16* __restrict__ D3, u16* __restrict__ D4, u16* __restrict__ D5)
{
    const int bx = blockIdx.x, tid = threadIdx.x;
    __shared__ float t[32][33];

    if (bx < 8192) {
        int i = bx * 256 + tid;
        float4 v = ((const float4*)h)[i];
        u16* o = hB + (long)i * 4;
        o[0] = f2bf(v.x); o[1] = f2bf(v.y); o[2] = f2bf(v.z); o[3] = f2bf(v.w);
    } else if (bx < 8704) {
        int i = (bx - 8192) * 256 + tid;
        int flat = i * 4;
        int b = flat >> 17, r = (flat >> 10) & 127, c = flat & 1023;
        float4 v = *(const float4*)(hc + ((long)b * 2048 + 1920 + r) * 1024 + c);
        u16* o = hcwB + (long)flat;
        o[0] = f2bf(v.x); o[1] = f2bf(v.y); o[2] = f2bf(v.z); o[3] = f2bf(v.w);
    } else if (bx < 8832) {
        int i = (bx - 8704) * 256 + tid;
        float4 v = ((const float4*)pos_w)[i];
        u16* o = pwB + (long)i * 4;
        o[0] = f2bf(v.x); o[1] = f2bf(v.y); o[2] = f2bf(v.z); o[3] = f2bf(v.w);
    } else if (bx < 8960) {
        int i = (bx - 8832) * 256 + tid;
        float4 v = ((const float4*)key_pe)[i];
        u16* o = kpeB + (long)i * 4;
        o[0] = f2bf(v.x); o[1] = f2bf(v.y); o[2] = f2bf(v.z); o[3] = f2bf(v.w);
    } else if (bx < 9024) {
        int e = (bx - 8960) * 256 + tid;
        if (e < 16384) WdB[(e & 15) * 1024 + (e >> 4)] = f2bf(Wd[e]);
    } else {
        const int t6 = bx - 9024;
        const int z = t6 >> 10;
        const int rem = t6 & 1023;
        const int bxx = rem & 31, byy = rem >> 5;
        const float* W = (z == 0) ? W0 : (z == 1) ? W1 : (z == 2) ? W2
                       : (z == 3) ? W3 : (z == 4) ? W4 : W5;
        u16* WT = (z == 0) ? D0 : (z == 1) ? D1 : (z == 2) ? D2
                : (z == 3) ? D3 : (z == 4) ? D4 : D5;
        const int tx = tid & 31, ty = tid >> 5;
        #pragma unroll
        for (int p = 0; p < 4; ++p) {
            int k = byy * 32 + ty + p * 8;
            t[ty + p * 8][tx] = W[(long)k * 1024 + bxx * 32 + tx];
        }
        __syncthreads();
        #pragma unroll
        for (int p = 0; p < 4; ++p) {
            int n = ty + p * 8;
            WT[((long)(bxx * 32 + n)) * 1024 + byy * 32 + tx] = f2bf(t[tx][n]);
        }
    }
}

// ---------------------------------------------------------------------------
// Fused QKV projection, 256x256 tile, 8 waves (512 thr), per-wave 128x64.
// 2 LDS buffers (64 KB), counted-vmcnt pipeline, raw barriers, XOR-swizzled
// LDS tiles. A (8192x1024) @ WqkvT^T (3072x1024). grid=(32,12).
// ---------------------------------------------------------------------------
__global__ __launch_bounds__(512) void gemm_qkv_big(
    const u16* __restrict__ A, const u16* __restrict__ Bt,
    u16* __restrict__ q_ws, u16* __restrict__ kbp, u16* __restrict__ vbp)
{
    const int tid = threadIdx.x;
    const int bm = blockIdx.x, bn = blockIdx.y;
    const int K = 1024, NT = 32;

    __shared__ __align__(16) u16 smem[65536 / 2];   // 64 KB
    u16* const As = smem;                            // [2][256*32] u16
    u16* const Bs = smem + 16384;

    const int lane = tid & 63, wv = tid >> 6;
    const int l15 = lane & 15, quad = lane >> 4;
    const int wm = (wv >> 2) * 128, wn = (wv & 3) * 64;

    f32x4 acc[8][4];
    #pragma unroll
    for (int i = 0; i < 8; ++i)
        #pragma unroll
        for (int j = 0; j < 4; ++j) acc[i][j] = (f32x4){0.f, 0.f, 0.f, 0.f};

    const int r_in = lane >> 2;
    const int col8 = (((lane & 3) ^ ((lane >> 3) & 3)) * 8);
    const bool isA = (wv < 4);
    const int crow0 = (isA ? wv : wv - 4) * 64;
    const u16* gb = isA ? (A + (long)(bm * 256 + crow0 + r_in) * K)
                        : (Bt + (long)(bn * 256 + crow0 + r_in) * K);
    const u16* s0 = gb + col8;
    const u16* s1 = s0 + (long)16 * K;
    const u16* s2 = s0 + (long)32 * K;
    const u16* s3 = s0 + (long)48 * K;
    u16* const lb = (isA ? As : Bs) + crow0 * 32;

    auto stage = [&](int buf) {
        u16* d = lb + buf * 8192;
        async16(s0, d);
        async16(s1, d + 512);
        async16(s2, d + 1024);
        async16(s3, d + 1536);
        s0 += 32; s1 += 32; s2 += 32; s3 += 32;
    };

    const int ssl = (quad ^ ((l15 >> 1) & 3)) * 8;   // swizzled read slot

    stage(0);
    for (int t = 0; t < NT; ++t) {
        __builtin_amdgcn_s_barrier();              // raw: WAR on buf[(t+1)&1]
        if (t + 1 < NT) {
            stage((t + 1) & 1);
            asm volatile("s_waitcnt vmcnt(4) lgkmcnt(0)\ns_barrier" ::: "memory");
        } else {
            asm volatile("s_waitcnt vmcnt(0) lgkmcnt(0)\ns_barrier" ::: "memory");
        }
        const u16* as = As + (t & 1) * 8192;
        const u16* bs = Bs + (t & 1) * 8192;
        short8 af[8], bfr[4];
        #pragma unroll
        for (int i = 0; i < 8; ++i)
            af[i] = *(const short8*)&as[(wm + i * 16 + l15) * 32 + ssl];
        #pragma unroll
        for (int j = 0; j < 4; ++j)
            bfr[j] = *(const short8*)&bs[(wn + j * 16 + l15) * 32 + ssl];
        #pragma unroll
        for (int i = 0; i < 8; ++i)
            #pragma unroll
            for (int j = 0; j < 4; ++j)
                acc[i][j] = __builtin_amdgcn_mfma_f32_16x16x32_bf16(af[i], bfr[j], acc[i][j], 0, 0, 0);
    }

    // ---- epilogue: two 128-row halves through LDS, coalesced stores ----
    const int mat = bn >> 2;                        // 0:q 1:k 2:v (uniform)
    u16* const outp = (mat == 0) ? q_ws : (mat == 1) ? kbp : vbp;
    const float scl = (mat == 0) ? 0.125f : 1.f;
    const int colbase = (bn & 3) * 256;
    #pragma unroll
    for (int hh = 0; hh < 2; ++hh) {
        __syncthreads();
        if ((wv >> 2) == hh) {
            #pragma unroll
            for (int i = 0; i < 8; ++i) {
                #pragma unroll
                for (int j = 0; j < 4; ++j) {
                    const int row = i * 16 + quad * 4;
                    const int col = wn + j * 16 + l15;
                    smem[(row + 0) * 256 + col] = f2bf(acc[i][j][0] * scl);
                    smem[(row + 1) * 256 + col] = f2bf(acc[i][j][1] * scl);
                    smem[(row + 2) * 256 + col] = f2bf(acc[i][j][2] * scl);
                    smem[(row + 3) * 256 + col] = f2bf(acc[i][j][3] * scl);
                }
            }
        }
        __syncthreads();
        #pragma unroll
        for (int k = 0; k < 8; ++k) {
            const int seg = tid + k * 512;
            const int row = seg >> 5, c16 = seg & 31;
            short8 v = *(const short8*)&smem[row * 256 + c16 * 8];
            *(short8*)(outp + (long)(bm * 256 + hh * 128 + row) * 1024 + colbase + c16 * 8) = v;
        }
    }
}

// ---------------------------------------------------------------------------
// Triple-buffered pipelined GEMM core (counted vmcnt, one barrier/iter),
// XOR-swizzled LDS. Tile 128x128, BK=32, K=1024 (NT=32), 4 waves.
// ---------------------------------------------------------------------------
#define GEMM_P3_BODY(EPILOGUE)                                                  \
    const int tid = threadIdx.x;                                                \
    const int bm = blockIdx.x, bn = blockIdx.y;                                 \
    const int K = 1024, NT = 32;                                                \
    __shared__ __align__(16) u16 As[3 * 128 * 32];                              \
    __shared__ __align__(16) u16 Bs[3 * 128 * 32];                              \
    const int lane = tid & 63, wv = tid >> 6;                                   \
    const int l15 = lane & 15, quad = lane >> 4;                                \
    const int wm = (wv & 1) * 64, wn = (wv >> 1) * 64;                          \
    f32x4 acc[4][4];                                                            \
    _Pragma("unroll")                                                           \
    for (int i = 0; i < 4; ++i)                                                 \
        _Pragma("unroll")                                                       \
        for (int j = 0; j < 4; ++j) acc[i][j] = (f32x4){0.f, 0.f, 0.f, 0.f};    \
    const int srow = wv * 32 + (lane >> 2);                                     \
    const int scol = (((lane & 3) ^ ((lane >> 3) & 3)) * 8);                    \
    const u16* a_src  = A  + (long)(bm * 128 + srow) * K + scol;                \
    const u16* a_src2 = a_src + (long)16 * K;                                   \
    const u16* b_src  = Bt + (long)(bn * 128 + srow) * K + scol;                \
    const u16* b_src2 = b_src + (long)16 * K;                                   \
    const int lofs0 = (wv * 32) * 32;                                           \
    const int lofs1 = (wv * 32 + 16) * 32;                                      \
    auto stage = [&](int t, int cur) {                                          \
        const int k0 = t * 32;                                                  \
        async16(a_src  + k0, &As[cur * 4096 + lofs0]);                          \
        async16(a_src2 + k0, &As[cur * 4096 + lofs1]);                          \
        async16(b_src  + k0, &Bs[cur * 4096 + lofs0]);                          \
        async16(b_src2 + k0, &Bs[cur * 4096 + lofs1]);                          \
    };                                                                          \
    stage(0, 0); stage(1, 1);                                                   \
    const int ssl = (quad ^ ((l15 >> 1) & 3)) * 8;                              \
    int cur = 0;                                                                \
    for (int t = 0; t < NT; ++t) {                                              \
        if (t == NT - 1)                                                        \
            asm volatile("s_waitcnt vmcnt(0) lgkmcnt(0)\ns_barrier" ::: "memory"); \
        else                                                                    \
            asm volatile("s_waitcnt vmcnt(4) lgkmcnt(0)\ns_barrier" ::: "memory"); \
        int nxt = cur + 2; if (nxt >= 3) nxt -= 3;                              \
        if (t + 2 < NT) stage(t + 2, nxt);                                      \
        const u16* as = &As[cur * 4096];                                        \
        const u16* bs = &Bs[cur * 4096];                                        \
        short8 af[4], bfr[4];                                                   \
        _Pragma("unroll")                                                       \
        for (int i = 0; i < 4; ++i)                                             \
            af[i] = *(const short8*)&as[(wm + i * 16 + l15) * 32 + ssl];        \
        _Pragma("unroll")                                                       \
        for (int j = 0; j < 4; ++j)                                             \
            bfr[j] = *(const short8*)&bs[(wn + j * 16 + l15) * 32 + ssl];       \
        _Pragma("unroll")                                                       \
        for (int i = 0; i < 4; ++i)                                             \
            _Pragma("unroll")                                                   \
            for (int j = 0; j < 4; ++j)                                         \
                acc[i][j] = __builtin_amdgcn_mfma_f32_16x16x32_bf16(af[i], bfr[j], acc[i][j], 0, 0, 0); \
        cur = (cur + 1 == 3) ? 0 : cur + 1;                                     \
    }                                                                           \
    EPILOGUE

// Output projection: A (8192x1024 bf16) @ WoT^T -> f32. grid=(64,8).
__global__ __launch_bounds__(256) void gemm_out3(
    const u16* __restrict__ A, const u16* __restrict__ Bt,
    float* __restrict__ Cf)
{
    GEMM_P3_BODY({
        _Pragma("unroll")
        for (int i = 0; i < 4; ++i) {
            _Pragma("unroll")
            for (int j = 0; j < 4; ++j) {
                int col = bn * 128 + wn + j * 16 + l15;
                _Pragma("unroll")
                for (int r = 0; r < 4; ++r) {
                    int row = bm * 128 + wm + i * 16 + quad * 4 + r;
                    Cf[(long)row * 1024 + col] = acc[i][j][r];
                }
            }
        }
    })
}

// ---------------------------------------------------------------------------
// Multi-job GEMM (m97 structure): six independent (A,Bt,C) jobs in one
// launch; z-grid partitioned, per-job bmN early-exit for ragged M.
// ---------------------------------------------------------------------------
struct GJob {
    const u16* A; long ab;
    const u16* Bt;
    float* Cf; u16* Cb; long cb;
    const float* bias; float scale;
    int bmN;
};

__device__ __forceinline__ void gemm_core128(
    const GJob& j, int bz, int bm, int bn, int N, int K)
{
    const int tid = threadIdx.x;
    const u16* A = j.A + (long)bz * j.ab;
    const long coff = (long)bz * j.cb;

    __shared__ __align__(16) u16 As[128 * 32];
    __shared__ __align__(16) u16 Bs[128 * 32];

    const int lane = tid & 63, wv = tid >> 6;
    const int l15 = lane & 15, quad = lane >> 4;
    const int wm = (wv & 1) * 64, wn = (wv >> 1) * 64;

    f32x4 acc[4][4];
    #pragma unroll
    for (int i = 0; i < 4; ++i)
        #pragma unroll
        for (int jx = 0; jx < 4; ++jx) acc[i][jx] = (f32x4){0.f, 0.f, 0.f, 0.f};

    const int srow = wv * 32 + (lane >> 2);
    const int scol = (lane & 3) * 8;
    const u16* a_src  = A    + (long)(bm * 128 + srow) * K + scol;
    const u16* a_src2 = a_src + (long)16 * K;
    const u16* b_src  = j.Bt + (long)(bn * 128 + srow) * K + scol;
    const u16* b_src2 = b_src + (long)16 * K;
    u16* lA0 = &As[(wv * 32) * 32];
    u16* lA1 = &As[(wv * 32 + 16) * 32];
    u16* lB0 = &Bs[(wv * 32) * 32];
    u16* lB1 = &Bs[(wv * 32 + 16) * 32];

    for (int k0 = 0; k0 < K; k0 += 32) {
        async16(a_src, lA0); async16(a_src2, lA1);
        async16(b_src, lB0); async16(b_src2, lB1);
        a_src += 32; a_src2 += 32; b_src += 32; b_src2 += 32;
        __syncthreads();
        short8 af[4], bfr[4];
        #pragma unroll
        for (int i = 0; i < 4; ++i)
            af[i] = *(const short8*)&As[(wm + i * 16 + l15) * 32 + quad * 8];
        #pragma unroll
        for (int jx = 0; jx < 4; ++jx)
            bfr[jx] = *(const short8*)&Bs[(wn + jx * 16 + l15) * 32 + quad * 8];
        #pragma unroll
        for (int i = 0; i < 4; ++i)
            #pragma unroll
            for (int jx = 0; jx < 4; ++jx)
                acc[i][jx] = __builtin_amdgcn_mfma_f32_16x16x32_bf16(af[i], bfr[jx], acc[i][jx], 0, 0, 0);
        __syncthreads();
    }

    #pragma unroll
    for (int i = 0; i < 4; ++i) {
        #pragma unroll
        for (int jx = 0; jx < 4; ++jx) {
            int col = bn * 128 + wn + jx * 16 + l15;
            float bsv = j.bias ? j.bias[col] : 0.f;
            #pragma unroll
            for (int r = 0; r < 4; ++r) {
                int row = bm * 128 + wm + i * 16 + quad * 4 + r;
                float v = acc[i][jx][r] * j.scale + bsv;
                long idx = coff + (long)row * N + col;
                if (j.Cf) j.Cf[idx] = v;
                if (j.Cb) j.Cb[idx] = f2bf(v);
            }
        }
    }
}

__global__ __launch_bounds__(256) void gemm_multi6(
    GJob j0, GJob j1, GJob j2, GJob j3, GJob j4, GJob j5,
    int n0, int n1, int n2, int n3, int n4, int N, int K)
{
    const int z = blockIdx.z;
    GJob j; int bz;
    if (z < n0)                          { j = j0; bz = z; }
    else if (z < n0 + n1)                { j = j1; bz = z - n0; }
    else if (z < n0 + n1 + n2)           { j = j2; bz = z - n0 - n1; }
    else if (z < n0 + n1 + n2 + n3)      { j = j3; bz = z - n0 - n1 - n2; }
    else if (z < n0 + n1 + n2 + n3 + n4) { j = j4; bz = z - n0 - n1 - n2 - n3; }
    else                                 { j = j5; bz = z - n0 - n1 - n2 - n3 - n4; }
    if ((int)blockIdx.x >= j.bmN) return;
    gemm_core128(j, bz, blockIdx.x, blockIdx.y, N, K);
}

// ---------------------------------------------------------------------------
// Per-chunk head scores via MFMA + WAVE-PARALLEL softmax and vectorized
// compress. grid=(64, B, 2): z=0 src=h_cache(f32)->hcm; z=1 src=hB->sc_blk.
// ---------------------------------------------------------------------------
__global__ __launch_bounds__(256) void scores_compress2(
    const float* __restrict__ hc, const u16* __restrict__ hBp,
    const u16* __restrict__ WdB, const float* __restrict__ bd,
    u16* __restrict__ hcm, float* __restrict__ sc_blk)
{
    const int c = blockIdx.x, b = blockIdx.y;
    const bool zc = (blockIdx.z == 0);
    const int tid = threadIdx.x;
    const int lane = tid & 63, wv = tid >> 6;
    const int l15 = lane & 15, quad = lane >> 4;

    __shared__ __align__(16) u16 srcs[32][1032];
    __shared__ float sred[4][32][16];
    __shared__ float s_sm[32][16];
    __shared__ float smx[4][16];
    __shared__ float ssum[4][16];

    if (zc) {
        const float* sb = hc + (long)b * 2048 * 1024 + (long)c * 32 * 1024;
        for (int e = tid; e < 8192; e += 256) {
            int flat = e * 4;
            int row = flat >> 10, col = flat & 1023;
            float4 v = *(const float4*)(sb + (long)row * 1024 + col);
            u16* dp = &srcs[row][col];
            dp[0] = f2bf(v.x); dp[1] = f2bf(v.y); dp[2] = f2bf(v.z); dp[3] = f2bf(v.w);
        }
    } else {
        const u16* sb = hBp + (long)b * 2048 * 1024 + (long)c * 32 * 1024;
        for (int e = tid; e < 4096; e += 256) {
            int flat = e * 8;
            int row = flat >> 10, col = flat & 1023;
            *(short8*)&srcs[row][col] = ldg8(sb + (long)row * 1024 + col);
        }
    }
    __syncthreads();

    // scores MFMA: wave wv covers K [wv*256, wv*256+256)
    {
        f32x4 acc0 = {0.f,0.f,0.f,0.f}, acc1 = {0.f,0.f,0.f,0.f};
        const int kq = wv * 256;
        #pragma unroll
        for (int kc = 0; kc < 8; ++kc) {
            int off = kq + kc * 32 + quad * 8;
            short8 bf_ = ldg8(WdB + (long)l15 * 1024 + off);
            short8 a0 = *(const short8*)&srcs[l15][off];
            short8 a1 = *(const short8*)&srcs[16 + l15][off];
            acc0 = __builtin_amdgcn_mfma_f32_16x16x32_bf16(a0, bf_, acc0, 0, 0, 0);
            acc1 = __builtin_amdgcn_mfma_f32_16x16x32_bf16(a1, bf_, acc1, 0, 0, 0);
        }
        #pragma unroll
        for (int r = 0; r < 4; ++r) {
            sred[wv][quad * 4 + r][l15]      = acc0[r];
            sred[wv][16 + quad * 4 + r][l15] = acc1[r];
        }
    }
    __syncthreads();
    for (int idx = tid; idx < 512; idx += 256) {
        int i = idx >> 4, hd = idx & 15;
        s_sm[i][hd] = bd[hd] + sred[0][i][hd] + sred[1][i][hd]
                            + sred[2][i][hd] + sred[3][i][hd];
    }
    __syncthreads();

    // ---- wave-parallel softmax over 32 rows per head ----
    // thread (i2, hd) = (tid>>4, tid&15) owns rows i2 and i2+16.
    {
        const int hd = tid & 15, i2 = tid >> 4;
        float a = s_sm[i2][hd], bx = s_sm[i2 + 16][hd];
        float m = fmaxf(a, bx);
        m = fmaxf(m, __shfl_xor(m, 16));
        m = fmaxf(m, __shfl_xor(m, 32));
        if (lane < 16) smx[wv][lane] = m;
        __syncthreads();
        float M = fmaxf(fmaxf(smx[0][hd], smx[1][hd]), fmaxf(smx[2][hd], smx[3][hd]));
        float ea = __expf(a - M), eb = __expf(bx - M);
        float s = ea + eb;
        s += __shfl_xor(s, 16);
        s += __shfl_xor(s, 32);
        if (lane < 16) ssum[wv][lane] = s;
        __syncthreads();
        float S = ssum[0][hd] + ssum[1][hd] + ssum[2][hd] + ssum[3][hd];
        float inv = 1.f / S;
        s_sm[i2][hd]      = ea * inv;
        s_sm[i2 + 16][hd] = eb * inv;
    }
    __syncthreads();

    if (!zc) {
        for (int idx = tid; idx < 512; idx += 256) {
            int hd = idx >> 5, i = idx & 31;
            sc_blk[(long)b * (16*64*32) + ((long)hd * 64 + c) * 32 + i] = s_sm[i][hd];
        }
    } else {
        // vectorized compress: thread pair (g, half) owns 8 cols of half rows.
        const int g = tid >> 1, half = tid & 1;     // g in [0,128)
        const int j0 = g * 8;
        const int hd = g >> 3;
        float acc[8] = {0.f,0.f,0.f,0.f,0.f,0.f,0.f,0.f};
        #pragma unroll
        for (int i = 0; i < 16; ++i) {
            const int row = half * 16 + i;
            const float w = s_sm[row][hd];
            short8 sv = *(const short8*)&srcs[row][j0];
            #pragma unroll
            for (int k = 0; k < 8; ++k) acc[k] += w * bf2f((u16)sv[k]);
        }
        #pragma unroll
        for (int k = 0; k < 8; ++k) acc[k] += __shfl_xor(acc[k], 1);
        if (half == 0) {
            u16 o[8];
            #pragma unroll
            for (int k = 0; k < 8; ++k) o[k] = f2bf(acc[k]);
            *(uint4*)&hcm[(long)b * (64*1024) + (long)c * 1024 + j0] = *(const uint4*)o;
        }
    }
}

// ---------------------------------------------------------------------------
// Post-QKV fused kernel. flat grid = 8704 + 512 = 9216.
// ---------------------------------------------------------------------------
__global__ __launch_bounds__(256) void post_qkv(
    const float* __restrict__ kcw, const float* __restrict__ vcw,
    const u16* __restrict__ kbp, const u16* __restrict__ vbp,
    float2* __restrict__ st_k, float2* __restrict__ st_v,
    const float* __restrict__ sc,
    const float* __restrict__ kc, const float* __restrict__ vc,
    const float* __restrict__ g, const float* __restrict__ be,
    u16* __restrict__ k_comp, u16* __restrict__ vcT)
{
    const int gr = blockIdx.x;
    const int tid = threadIdx.x;
    const int lane = tid & 63, wv = tid >> 6;

    if (gr < 8704) {
        float sm1 = 0.f, sq1 = 0.f, sm2 = 0.f, sq2 = 0.f;
        long dst;
        if (gr < 512) {
            const int b = gr >> 7, r = gr & 127;
            const float* p1 = kcw + ((long)b * 128 + r) * 1024;
            const float* p2 = vcw + ((long)b * 128 + r) * 1024;
            #pragma unroll
            for (int p = 0; p < 4; ++p) {
                float x = p1[tid + p * 256];
                float y = p2[tid + p * 256];
                sm1 += x; sq1 += x * x;
                sm2 += y; sq2 += y * y;
            }
            dst = (long)b * 2176 + r;
        } else {
            const int g2 = gr - 512;
            const int b = g2 >> 11, r = g2 & 2047;
            const u16* p1 = kbp + ((long)b * 2048 + r) * 1024 + tid * 4;
            const u16* p2 = vbp + ((long)b * 2048 + r) * 1024 + tid * 4;
            uint2 v1 = *(const uint2*)p1;
            uint2 v2 = *(const uint2*)p2;
            const u16* a1 = (const u16*)&v1;
            const u16* a2 = (const u16*)&v2;
            #pragma unroll
            for (int p = 0; p < 4; ++p) {
                float x = bf2f(a1[p]);
                float y = bf2f(a2[p]);
                sm1 += x; sq1 += x * x;
                sm2 += y; sq2 += y * y;
            }
            dst = (long)b * 2176 + 128 + r;
        }

        __shared__ float red[4][4];
        for (int off = 32; off; off >>= 1) {
            sm1 += __shfl_xor(sm1, off); sq1 += __shfl_xor(sq1, off);
            sm2 += __shfl_xor(sm2, off); sq2 += __shfl_xor(sq2, off);
        }
        if (lane == 0) { red[0][wv] = sm1; red[1][wv] = sq1; red[2][wv] = sm2; red[3][wv] = sq2; }
        __syncthreads();
        if (tid == 0) {
            sm1 = red[0][0] + red[0][1] + red[0][2] + red[0][3];
            sq1 = red[1][0] + red[1][1] + red[1][2] + red[1][3];
            sm2 = red[2][0] + red[2][1] + red[2][2] + red[2][3];
            sq2 = red[3][0] + red[3][1] + red[3][2] + red[3][3];
            float m1 = sm1 * (1.f / 1024.f);
            float i1 = rsqrtf(fmaxf(sq1 * (1.f / 1024.f) - m1 * m1, 0.f) + 1e-5f);
            float m2 = sm2 * (1.f / 1024.f);
            float i2 = rsqrtf(fmaxf(sq2 * (1.f / 1024.f) - m2 * m2, 0.f) + 1e-5f);
            st_k[dst] = make_float2(m1, i1);
            st_v[dst] = make_float2(m2, i2);
        }
        return;
    }

    const int idx = gr - 8704;                 // 0..511
    const int zz = idx >> 8;                   // 0..1
    const int b = (idx >> 6) & 3;
    const int cx = idx & 63;

    if (zz == 0) {
        const int c = cx;
        __shared__ float scw[16][32];
        __shared__ float red[4][4];

        for (int i2 = tid; i2 < 512; i2 += 256) {
            int hd = i2 >> 5, i = i2 & 31;
            scw[hd][i] = sc[((long)(b * 16 + hd) * 64 + c) * 32 + i];
        }
        __syncthreads();

        const int j0 = tid * 4;
        const int hd = j0 >> 6;
        float xk[4] = {0.f,0.f,0.f,0.f}, xv[4] = {0.f,0.f,0.f,0.f};
        const u16* kb = kbp + ((long)b * 2048 + c * 32) * 1024 + j0;
        const u16* vb = vbp + ((long)b * 2048 + c * 32) * 1024 + j0;
        for (int i = 0; i < 32; ++i) {
            float w = scw[hd][i];
            uint2 kr = *(const uint2*)(kb + (long)i * 1024);
            uint2 vr = *(const uint2*)(vb + (long)i * 1024);
            const u16* kp = (const u16*)&kr;
            const u16* vp = (const u16*)&vr;
            #pragma unroll
            for (int p = 0; p < 4; ++p) {
                xk[p] += w * bf2f(kp[p]);
                xv[p] += w * bf2f(vp[p]);
            }
        }
        float sk = 0.f, qk = 0.f, sv = 0.f, qv = 0.f;
        #pragma unroll
        for (int p = 0; p < 4; ++p) { sk += xk[p]; qk += xk[p]*xk[p]; sv += xv[p]; qv += xv[p]*xv[p]; }
        for (int off = 32; off; off >>= 1) {
            sk += __shfl_xor(sk, off); qk += __shfl_xor(qk, off);
            sv += __shfl_xor(sv, off); qv += __shfl_xor(qv, off);
        }
        if (lane == 0) { red[0][wv] = sk; red[1][wv] = qk; red[2][wv] = sv; red[3][wv] = qv; }
        __syncthreads();
        sk = red[0][0] + red[0][1] + red[0][2] + red[0][3];
        qk = red[1][0] + red[1][1] + red[1][2] + red[1][3];
        sv = red[2][0] + red[2][1] + red[2][2] + red[2][3];
        qv = red[3][0] + red[3][1] + red[3][2] + red[3][3];
        const float inv_n = 1.f / 1024.f;
        float mk = sk * inv_n, mv = sv * inv_n;
        float ik = rsqrtf(fmaxf(qk * inv_n - mk * mk, 0.f) + 1e-5f);
        float iv = rsqrtf(fmaxf(qv * inv_n - mv * mv, 0.f) + 1e-5f);
        float4 g4 = *(const float4*)(g + j0);
        float4 b4 = *(const float4*)(be + j0);
        float gg[4] = {g4.x, g4.y, g4.z, g4.w};
        float bb[4] = {b4.x, b4.y, b4.z, b4.w};
        u16 ko[4];
        #pragma unroll
        for (int p = 0; p < 4; ++p) ko[p] = f2bf((xk[p] - mk) * ik * gg[p] + bb[p]);
        *(uint2*)&k_comp[((long)b * 128 + 64 + c) * 1024 + j0] = *(const uint2*)ko;
        #pragma unroll
        for (int p = 0; p < 4; ++p)
            vcT[((long)b * 1024 + j0 + p) * 128 + 64 + c] = f2bf((xv[p] - mv) * iv * gg[p] + bb[p]);
    } else {
        const int r = cx;
        const float* pk = kc + ((long)b * 64 + r) * 1024;
        const float* pv = vc + ((long)b * 64 + r) * 1024;

        __shared__ float red2[4][4];
        float xk[4], xv[4];
        float smk = 0.f, sqk = 0.f, smv = 0.f, sqv = 0.f;
        #pragma unroll
        for (int p = 0; p < 4; ++p) {
            xk[p] = pk[tid + p * 256];
            xv[p] = pv[tid + p * 256];
            smk += xk[p]; sqk += xk[p] * xk[p];
            smv += xv[p]; sqv += xv[p] * xv[p];
        }
        for (int off = 32; off; off >>= 1) {
            smk += __shfl_xor(smk, off); sqk += __shfl_xor(sqk, off);
            smv += __shfl_xor(smv, off); sqv += __shfl_xor(sqv, off);
        }
        if (lane == 0) { red2[0][wv] = smk; red2[1][wv] = sqk; red2[2][wv] = smv; red2[3][wv] = sqv; }
        __syncthreads();
        smk = red2[0][0] + red2[0][1] + red2[0][2] + red2[0][3];
        sqk = red2[1][0] + red2[1][1] + red2[1][2] + red2[1][3];
        smv = red2[2][0] + red2[2][1] + red2[2][2] + red2[2][3];
        sqv = red2[3][0] + red2[3][1] + red2[3][2] + red2[3][3];
        const float inv_n = 1.f / 1024.f;
        float mk = smk * inv_n, mv = smv * inv_n;
        float ik = rsqrtf(fmaxf(sqk * inv_n - mk * mk, 0.f) + 1e-5f);
        float iv = rsqrtf(fmaxf(sqv * inv_n - mv * mv, 0.f) + 1e-5f);
        #pragma unroll
        for (int p = 0; p < 4; ++p) {
            int j = tid + p * 256;
            k_comp[((long)b * 128 + r) * 1024 + j] = f2bf((xk[p] - mk) * ik * g[j] + be[j]);
            vcT[((long)b * 1024 + j) * 128 + r]    = f2bf((xv[p] - mv) * iv * g[j] + be[j]);
        }
    }
}

// ---------------------------------------------------------------------------
// Materialize window K (bf16 (B,2176,1024)) and V^T (bf16 (B,1024,2176),
// col = concat_row - 1).  grid=(34, 16, B). kbp/vbp are bf16.
// ---------------------------------------------------------------------------
__global__ __launch_bounds__(256) void win_apply(
    const float* __restrict__ kcw, const float* __restrict__ vcw,
    const u16* __restrict__ kbp, const u16* __restrict__ vbp,
    const float2* __restrict__ st_kw, const float2* __restrict__ st_vw,
    const float* __restrict__ g_w, const float* __restrict__ b_w,
    u16* __restrict__ kwin, u16* __restrict__ vwinT)
{
    const int tt = blockIdx.x, dc = blockIdx.y, b = blockIdx.z;
    const int t0 = tt * 64, d0 = dc * 64;
    const int tid = threadIdx.x;

    __shared__ u16 vt[64][74];

    const int r = tid >> 2;
    const int dsub = (tid & 3) * 16;
    const int t = t0 + r;
    float2 sk = st_kw[(long)b * 2176 + t];
    float2 sv = st_vw[(long)b * 2176 + t];
    const float* ksf = kcw + ((long)b * 128 + t) * 1024;
    const float* vsf = vcw + ((long)b * 128 + t) * 1024;
    const u16*   ksb = kbp + ((long)b * 2048 + t - 128) * 1024;
    const u16*   vsb = vbp + ((long)b * 2048 + t - 128) * 1024;
    #pragma unroll
    for (int j = 0; j < 16; j += 4) {
        int d = d0 + dsub + j;
        float4 kv, vv;
        if (t < 128) {
            kv = *(const float4*)(ksf + d);
            vv = *(const float4*)(vsf + d);
        } else {
            uint2 kr = *(const uint2*)(ksb + d);
            uint2 vr = *(const uint2*)(vsb + d);
            const u16* kp = (const u16*)&kr;
            const u16* vp = (const u16*)&vr;
            kv = make_float4(bf2f(kp[0]), bf2f(kp[1]), bf2f(kp[2]), bf2f(kp[3]));
            vv = make_float4(bf2f(vp[0]), bf2f(vp[1]), bf2f(vp[2]), bf2f(vp[3]));
        }
        float4 g4 = *(const float4*)(g_w + d);
        float4 b4 = *(const float4*)(b_w + d);
        u16 ko[4];
        ko[0] = f2bf((kv.x - sk.x) * sk.y * g4.x + b4.x);
        ko[1] = f2bf((kv.y - sk.x) * sk.y * g4.y + b4.y);
        ko[2] = f2bf((kv.z - sk.x) * sk.y * g4.z + b4.z);
        ko[3] = f2bf((kv.w - sk.x) * sk.y * g4.w + b4.w);
        *(uint2*)&kwin[((long)b * 2176 + t) * 1024 + d] = *(const uint2*)ko;
        vt[r][dsub + j + 0] = f2bf((vv.x - sv.x) * sv.y * g4.x + b4.x);
        vt[r][dsub + j + 1] = f2bf((vv.y - sv.x) * sv.y * g4.y + b4.y);
        vt[r][dsub + j + 2] = f2bf((vv.z - sv.x) * sv.y * g4.z + b4.z);
        vt[r][dsub + j + 3] = f2bf((vv.w - sv.x) * sv.y * g4.w + b4.w);
    }
    __syncthreads();
    #pragma unroll
    for (int pass = 0; pass < 16; ++pass) {
        int dd = (tid >> 6) + pass * 4;
        int rr = tid & 63;
        int crow = t0 + rr;
        if (crow >= 1)
            vwinT[((long)b * 1024 + d0 + dd) * 2176 + crow - 1] = vt[rr][dd];
    }
}

// ---------------------------------------------------------------------------
// Fused MFMA attention: one block per (h, qc, b), 256 thr = 4 waves.
// Grid x = h (fastest) so 16 consecutive blocks share kwb/vwT rows -> L2.
// LDS = L (32x260 f32) + qa (32x72 bf16) = 37.9 KB -> 4 blocks/CU.
// S1 K-window rows prefetched into regs BEFORE the q barrier (issue-early);
// PV B-operands prefetched before softmax.
// ---------------------------------------------------------------------------
__global__ __launch_bounds__(256, 4) void attention(
    const u16* __restrict__ qb,     // (B,2048,1024) bf16, already /8
    const u16* __restrict__ kcb,    // (B,128,1024) bf16
    const u16* __restrict__ vcT,    // (B,1024,128) bf16 transposed
    const u16* __restrict__ kwb,    // (B,2176,1024) bf16
    const u16* __restrict__ vwT,    // (B,1024,2176) bf16 transposed, col=row-1
    const u16* __restrict__ pcb,    // (128,1024) bf16
    const u16* __restrict__ ptb,    // (128,1024) bf16
    const float* __restrict__ r_w,  // (16,64)
    const float* __restrict__ r_r,
    u16* __restrict__ attn_o)       // (B,2048,1024) bf16
{
    const int h = blockIdx.x, qc = blockIdx.y, b = blockIdx.z;
    const int l0 = qc * 32;
    const int tid = threadIdx.x;
    const int lane = tid & 63, wv = tid >> 6;
    const int l15 = lane & 15, quad = lane >> 4;

    __shared__ __align__(16) float L[32 * 260];     // logits; P aliases row tails
    __shared__ __align__(16) u16 qa[32][72];        // plain q (bf16)
    u16* Lu = (u16*)L;                              // row stride 520 u16

    // ---- stage q ----
    {
        const int r = tid >> 3, d0 = (tid & 7) * 8;
        short8 qv = ldg8(qb + ((long)(b * 2048 + l0 + r)) * 1024 + h * 64 + d0);
        *(short8*)&qa[r][d0] = qv;
    }

    // ---- prefetch S1 K-window rows into regs (issued before the barrier) ----
    short8 s1k[3][2];
    int nw = 0;
    #pragma unroll
    for (int i = 0; i < 3; ++i) {
        const int nt = wv + i * 4;
        if (nt < 10) {
            int t = nt * 16 + l15;
            int row = l0 + 1 + t; if (row > 2175) row = 2175;
            const u16* kp = kwb + ((long)(b * 2176 + row)) * 1024 + h * 64 + quad * 8;
            s1k[i][0] = ldg8(kp);
            s1k[i][1] = ldg8(kp + 32);
            nw = i + 1;
        }
    }
    __syncthreads();

    __builtin_amdgcn_s_setprio(1);
    // ---- S_c: q·k_comp + q·pos_c[64+ci-qc], tiles 2wv..2wv+1 ----
    #pragma unroll
    for (int ti = 0; ti < 2; ++ti) {
        int n0 = (wv * 2 + ti) * 16;
        int ci = n0 + l15;
        f32x4 a0 = {0.f,0.f,0.f,0.f}, a1 = {0.f,0.f,0.f,0.f};
        if (n0 < 64 + qc) {
            int p = 64 + ci - qc; if (p > 127) p = 127;
            #pragma unroll
            for (int kc = 0; kc < 2; ++kc) {
                int k0 = kc * 32;
                short8 bk = ldg8(kcb + ((long)(b * 128 + ci)) * 1024 + h * 64 + k0 + quad * 8);
                short8 bp = ldg8(pcb + (long)p * 1024 + h * 64 + k0 + quad * 8);
                short8 fa0 = *(const short8*)&qa[l15][k0 + quad * 8];
                short8 fa1 = *(const short8*)&qa[16 + l15][k0 + quad * 8];
                a0 = __builtin_amdgcn_mfma_f32_16x16x32_bf16(fa0, bk, a0, 0, 0, 0);
                a0 = __builtin_amdgcn_mfma_f32_16x16x32_bf16(fa0, bp, a0, 0, 0, 0);
                a1 = __builtin_amdgcn_mfma_f32_16x16x32_bf16(fa1, bk, a1, 0, 0, 0);
                a1 = __builtin_amdgcn_mfma_f32_16x16x32_bf16(fa1, bp, a1, 0, 0, 0);
            }
        }
        bool msk = (ci >= 64 + qc);
        #pragma unroll
        for (int r = 0; r < 4; ++r) {
            L[(quad * 4 + r) * 260 + ci]      = msk ? NEGINF : a0[r];
            L[(16 + quad * 4 + r) * 260 + ci] = msk ? NEGINF : a1[r];
        }
    }

    // ---- S2: (q+r_r)·pos_t; biased frags built in registers ----
    {
        short8 qf[2][2];
        #pragma unroll
        for (int kc = 0; kc < 2; ++kc) {
            const int off = kc * 32 + quad * 8;
            const float* bp_ = r_r + h * 64 + off;
            float4 b0 = *(const float4*)bp_;
            float4 b1 = *(const float4*)(bp_ + 4);
            float bb[8] = {b0.x,b0.y,b0.z,b0.w,b1.x,b1.y,b1.z,b1.w};
            #pragma unroll
            for (int hf = 0; hf < 2; ++hf) {
                short8 qv = *(const short8*)&qa[hf * 16 + l15][off];
                short8 f;
                #pragma unroll
                for (int j = 0; j < 8; ++j) f[j] = (short)f2bf(bf2f((u16)qv[j]) + bb[j]);
                qf[kc][hf] = f;
            }
        }
        #pragma unroll
        for (int ti = 0; ti < 2; ++ti) {
            int w0 = (wv * 2 + ti) * 16;
            int w = w0 + l15;
            f32x4 a0 = {0.f,0.f,0.f,0.f}, a1 = {0.f,0.f,0.f,0.f};
            #pragma unroll
            for (int kc = 0; kc < 2; ++kc) {
                int k0 = kc * 32;
                short8 bp = ldg8(ptb + (long)w * 1024 + h * 64 + k0 + quad * 8);
                a0 = __builtin_amdgcn_mfma_f32_16x16x32_bf16(qf[kc][0], bp, a0, 0, 0, 0);
                a1 = __builtin_amdgcn_mfma_f32_16x16x32_bf16(qf[kc][1], bp, a1, 0, 0, 0);
            }
            #pragma unroll
            for (int r = 0; r < 4; ++r) {
                L[(quad * 4 + r) * 260 + 128 + w]      = a0[r];
                L[(16 + quad * 4 + r) * 260 + 128 + w] = a1[r];
            }
        }
    }

    // ---- S1: (q+r_w)·k_win MFMAs from prefetched regs ----
    f32x4 s1a[3], s1b[3];
    {
        short8 qf[2][2];
        #pragma unroll
        for (int kc = 0; kc < 2; ++kc) {
            const int off = kc * 32 + quad * 8;
            const float* bp_ = r_w + h * 64 + off;
            float4 b0 = *(const float4*)bp_;
            float4 b1 = *(const float4*)(bp_ + 4);
            float bb[8] = {b0.x,b0.y,b0.z,b0.w,b1.x,b1.y,b1.z,b1.w};
            #pragma unroll
            for (int hf = 0; hf < 2; ++hf) {
                short8 qv = *(const short8*)&qa[hf * 16 + l15][off];
                short8 f;
                #pragma unroll
                for (int j = 0; j < 8; ++j) f[j] = (short)f2bf(bf2f((u16)qv[j]) + bb[j]);
                qf[kc][hf] = f;
            }
        }
        #pragma unroll
        for (int i = 0; i < 3; ++i) {
            if (i < nw) {
                f32x4 a0 = {0.f,0.f,0.f,0.f}, a1 = {0.f,0.f,0.f,0.f};
                #pragma unroll
                for (int kc = 0; kc < 2; ++kc) {
                    a0 = __builtin_amdgcn_mfma_f32_16x16x32_bf16(qf[kc][0], s1k[i][kc], a0, 0, 0, 0);
                    a1 = __builtin_amdgcn_mfma_f32_16x16x32_bf16(qf[kc][1], s1k[i][kc], a1, 0, 0, 0);
                }
                s1a[i] = a0; s1b[i] = a1;
            }
        }
    }
    __builtin_amdgcn_s_setprio(0);
    __syncthreads();
    // band add: L[row][128 + (t-row)] += S1
    #pragma unroll
    for (int i = 0; i < 3; ++i) {
        if (i < nw) {
            int t = (wv + i * 4) * 16 + l15;
            #pragma unroll
            for (int r = 0; r < 4; ++r) {
                int r0 = quad * 4 + r;
                int w0 = t - r0;
                if (w0 >= 0 && w0 < 128) L[r0 * 260 + 128 + w0] += s1a[i][r];
                int r1 = 16 + quad * 4 + r;
                int w1 = t - r1;
                if (w1 >= 0 && w1 < 128) L[r1 * 260 + 128 + w1] += s1b[i][r];
            }
        }
    }
    __syncthreads();

    // ---- prefetch PV B-operands into registers (hide latency under softmax)
    const int n0d = wv * 16;
    short8 bvv[9];
    {
        const u16* vc = vcT + ((long)(b * 1024 + h * 64 + n0d + l15)) * 128 + quad * 8;
        #pragma unroll
        for (int kc = 0; kc < 4; ++kc) bvv[kc] = ldg8(vc + kc * 32);
        const u16* vw = vwT + ((long)(b * 1024 + h * 64 + n0d + l15)) * 2176 + l0 + quad * 8;
        #pragma unroll
        for (int kc = 0; kc < 5; ++kc) bvv[4 + kc] = ldg8(vw + kc * 32);
    }

    // ---- softmax: wave wv owns rows wv*8..wv*8+7; lane holds cols 4l..4l+3.
    #pragma unroll
    for (int rr = 0; rr < 8; ++rr) {
        const int r = wv * 8 + rr;
        float4 v = *(const float4*)&L[r * 260 + lane * 4];
        float m = fmaxf(fmaxf(v.x, v.y), fmaxf(v.z, v.w));
        for (int off = 32; off; off >>= 1) m = fmaxf(m, __shfl_xor(m, off));
        float e0 = __expf(v.x - m), e1 = __expf(v.y - m);
        float e2 = __expf(v.z - m), e3 = __expf(v.w - m);
        float s = (e0 + e1) + (e2 + e3);
        for (int off = 32; off; off >>= 1) s += __shfl_xor(s, off);
        float inv = 1.f / s;
        e0 *= inv; e1 *= inv; e2 *= inv; e3 *= inv;
        u16* rowP = Lu + (long)r * 520;
        if (lane < 32) {
            u16 pk[4] = {f2bf(e0), f2bf(e1), f2bf(e2), f2bf(e3)};
            *(uint2*)&rowP[lane * 4] = *(const uint2*)pk;
        } else {
            const int l = lane - 32;          // 0..31
            const int t = 4 * l + r;          // band: t = w + r
            u16* p = rowP + 160 + t;
            p[0] = f2bf(e0); p[1] = f2bf(e1); p[2] = f2bf(e2); p[3] = f2bf(e3);
            const int tz = (l < r) ? l : 128 + l;
            rowP[160 + tz] = 0;
        }
    }
    __syncthreads();

    // ---- PV: wave wv -> d-tile wv*16 (B-operands already in registers) ----
    __builtin_amdgcn_s_setprio(1);
    f32x4 o0 = {0.f,0.f,0.f,0.f}, o1 = {0.f,0.f,0.f,0.f};
    #pragma unroll
    for (int kc = 0; kc < 4; ++kc) {           // compressed, K=128
        int k0 = kc * 32;
        short8 av0 = *(const short8*)(Lu + (long)l15 * 520 + k0 + quad * 8);
        short8 av1 = *(const short8*)(Lu + (long)(16 + l15) * 520 + k0 + quad * 8);
        o0 = __builtin_amdgcn_mfma_f32_16x16x32_bf16(av0, bvv[kc], o0, 0, 0, 0);
        o1 = __builtin_amdgcn_mfma_f32_16x16x32_bf16(av1, bvv[kc], o1, 0, 0, 0);
    }
    #pragma unroll
    for (int kc = 0; kc < 5; ++kc) {           // windowed, K=160 banded
        int k0 = kc * 32;
        short8 av0 = *(const short8*)(Lu + (long)l15 * 520 + 160 + k0 + quad * 8);
        short8 av1 = *(const short8*)(Lu + (long)(16 + l15) * 520 + 160 + k0 + quad * 8);
        o0 = __builtin_amdgcn_mfma_f32_16x16x32_bf16(av0, bvv[4 + kc], o0, 0, 0, 0);
        o1 = __builtin_amdgcn_mfma_f32_16x16x32_bf16(av1, bvv[4 + kc], o1, 0, 0, 0);
    }
    __builtin_amdgcn_s_setprio(0);
    #pragma unroll
    for (int r = 0; r < 4; ++r) {
        int r0 = quad * 4 + r, r1 = 16 + quad * 4 + r;
        attn_o[((long)(b * 2048 + l0 + r0)) * 1024 + h * 64 + n0d + l15] = f2bf(o0[r]);
        attn_o[((long)(b * 2048 + l0 + r1)) * 1024 + h * 64 + n0d + l15] = f2bf(o1[r]);
    }
}

// ---------------------------------------------------------------------------
extern "C" void kernel_launch(void* const* d_in, const int* in_sizes, int n_in,
                              void* d_out, int out_size, void* d_ws, size_t ws_size,
                              hipStream_t stream)
{
    (void)in_sizes; (void)n_in; (void)out_size; (void)ws_size;

    const float* h       = (const float*)d_in[0];
    const float* h_cache = (const float*)d_in[1];
    const float* key_pe  = (const float*)d_in[2];
    const float* pos_w   = (const float*)d_in[3];
    const float* Wq      = (const float*)d_in[4];
    const float* Wk      = (const float*)d_in[5];
    const float* Wv      = (const float*)d_in[6];
    const float* Wo      = (const float*)d_in[7];
    const float* Wd      = (const float*)d_in[8];
    const float* bd      = (const float*)d_in[9];
    const float* Wr      = (const float*)d_in[10];
    const float* br      = (const float*)d_in[11];
    const float* Wrc     = (const float*)d_in[12];
    const float* brc     = (const float*)d_in[13];
    const float* r_r     = (const float*)d_in[14];
    const float* r_w     = (const float*)d_in[15];
    const float* g_d     = (const float*)d_in[16];
    const float* b_d     = (const float*)d_in[17];
    const float* g_w     = (const float*)d_in[18];
    const float* b_w     = (const float*)d_in[19];

    char* ws = (char*)d_ws;
    size_t off = 0;
    auto alloc = [&](size_t bytes) -> void* {
        void* p = ws + off; off += (bytes + 255) & ~(size_t)255; return p;
    };
    // bf16 casts / transposed weights (N,K)
    u16* hB     = (u16*)alloc((size_t)8192 * 1024 * 2);
    u16* hcwB   = (u16*)alloc((size_t)4 * 128 * 1024 * 2);
    u16* WqkvT  = (u16*)alloc((size_t)3 * 1024 * 1024 * 2);   // Wq|Wk|Wv stacked
    u16* WoT    = (u16*)alloc((size_t)1024 * 1024 * 2);
    u16* WrT    = (u16*)alloc((size_t)1024 * 1024 * 2);
    u16* WrcT   = (u16*)alloc((size_t)1024 * 1024 * 2);
    u16* pwB    = (u16*)alloc((size_t)128 * 1024 * 2);
    u16* kpeB   = (u16*)alloc((size_t)128 * 1024 * 2);
    u16* WdB    = (u16*)alloc((size_t)16 * 1024 * 2);
    // intermediates
    u16*   q_ws   = (u16*)alloc((size_t)8192 * 1024 * 2);
    u16*   kbp    = (u16*)alloc((size_t)8192 * 1024 * 2);     // bf16
    u16*   vbp    = (u16*)alloc((size_t)8192 * 1024 * 2);     // bf16
    u16*   attn_o = (u16*)alloc((size_t)8192 * 1024 * 2);
    float* kcw    = (float*)alloc((size_t)4 * 128 * 1024 * 4);
    float* vcw    = (float*)alloc((size_t)4 * 128 * 1024 * 4);
    u16*   hcm    = (u16*)alloc((size_t)4 * 64 * 1024 * 2);
    float* kc_raw = (float*)alloc((size_t)4 * 64 * 1024 * 4);
    float* vc_raw = (float*)alloc((size_t)4 * 64 * 1024 * 4);
    float* sc_blk = (float*)alloc((size_t)4 * 16 * 64 * 32 * 4);
    u16*   k_comp = (u16*)alloc((size_t)4 * 128 * 1024 * 2);
    u16*   vcT    = (u16*)alloc((size_t)4 * 1024 * 128 * 2);
    float2* st_kw = (float2*)alloc((size_t)4 * 2176 * 8);
    float2* st_vw = (float2*)alloc((size_t)4 * 2176 * 8);
    u16*   pos_tb = (u16*)alloc((size_t)128 * 1024 * 2);
    u16*   pos_cb = (u16*)alloc((size_t)128 * 1024 * 2);
    u16*   kwin   = (u16*)alloc((size_t)4 * 2176 * 1024 * 2);
    u16*   vwinT  = (u16*)alloc((size_t)4 * 1024 * 2176 * 2 + 256);

    const u16* WkT = WqkvT + (size_t)1024 * 1024;
    const u16* WvT = WqkvT + (size_t)2 * 1024 * 1024;

    const dim3 blk(256);

    // all casts + weight transposes in ONE launch
    cast_fuse<<<dim3(15168), blk, 0, stream>>>(
        h, h_cache, pos_w, key_pe, Wd, hB, hcwB, pwB, kpeB, WdB,
        Wq, Wk, Wv, Wo, Wr, Wrc,
        WqkvT, WqkvT + (size_t)1024*1024, WqkvT + (size_t)2*1024*1024,
        WoT, WrT, WrcT);

    // scores + compress, both jobs in one launch (hcm needed by small GEMMs)
    scores_compress2<<<dim3(64,4,2), blk, 0, stream>>>(h_cache, hB, WdB, bd, hcm, sc_blk);

    // ALL six small GEMMs in ONE launch (z = 4+4+1+1+1+1 = 12)
    {
        GJob jk  = { hcwB, (long)128*1024, WkT, kcw, nullptr, (long)128*1024, nullptr, 1.f, 1 };
        GJob jv  = { hcwB, (long)128*1024, WvT, vcw, nullptr, (long)128*1024, nullptr, 1.f, 1 };
        GJob jt  = { pwB,  0, WrT,  nullptr, pos_tb, 0, br,  1.f, 1 };
        GJob jc  = { kpeB, 0, WrcT, nullptr, pos_cb, 0, brc, 1.f, 1 };
        GJob jkc = { hcm, 0, WkT, kc_raw, nullptr, 0, nullptr, 1.f, 2 };
        GJob jvc = { hcm, 0, WvT, vc_raw, nullptr, 0, nullptr, 1.f, 2 };
        gemm_multi6<<<dim3(2,8,12), blk, 0, stream>>>(jk, jv, jt, jc, jkc, jvc,
                                                      4, 4, 1, 1, 1, 1024, 1024);
    }

    // fused QKV projection (M=8192, N=3072): 256x256-tile 8-wave pipeline
    gemm_qkv_big<<<dim3(32,12), dim3(512), 0, stream>>>(hB, WqkvT, q_ws, kbp, vbp);

    // window-LN stats + compress+LN for k_comp/vcT, ONE launch (9216 blocks)
    post_qkv<<<dim3(9216), blk, 0, stream>>>(kcw, vcw, kbp, vbp, st_kw, st_vw,
                                             sc_blk, kc_raw, vc_raw, g_d, b_d,
                                             k_comp, vcT);

    win_apply<<<dim3(34,16,4), blk, 0, stream>>>(kcw, vcw, kbp, vbp, st_kw, st_vw, g_w, b_w, kwin, vwinT);

    // attention (grid: h fastest for kwb/vwT L2 sharing)
    attention<<<dim3(16,64,4), blk, 0, stream>>>(q_ws, k_comp, vcT, kwin, vwinT,
                                                 pos_cb, pos_tb, r_w, r_r, attn_o);
    // output projection, pipelined
    gemm_out3<<<dim3(64,8,1), blk, 0, stream>>>(attn_o, WoT, (float*)d_out);
}